// Round 1
// baseline (6567.452 us; speedup 1.0000x reference)
//
#include <hip/hip_runtime.h>
#include <cstddef>
#include <cstdint>

#define N_NODES 170
#define SEQ 12
#define BATCH 32
#define DM 120
#define BT (BATCH*SEQ)          // 384
#define ROWS (BT*N_NODES)       // 65280
#define FF 2048

// ---------------- workspace layout (in floats, 16-float aligned) ----------------
static constexpr size_t OFF_A   = 0;                       // 3*170*170 = 86700
static constexpr size_t OFF_A2  = 86704;
static constexpr size_t OFF_G   = 173408;
static constexpr size_t OFF_L   = 260112;
static constexpr size_t OFF_RS1 = 346816;                  // 3*170
static constexpr size_t OFF_RS2 = 347328;
static constexpr size_t OFF_RS3 = 347840;
static constexpr size_t OFF_Y1  = 348416;                  // 7,833,600 each below
static constexpr size_t OFF_Y2  = OFF_Y1 + 7833600;
static constexpr size_t OFF_HQ  = OFF_Y2 + 7833600;
static constexpr size_t OFF_HK  = OFF_HQ + 7833600;
static constexpr size_t OFF_HV  = OFF_HK + 7833600;
static constexpr size_t OFF_LN1 = OFF_HV + 7833600;
// total = 47,350,016 floats = 189.4 MB

// ---------------- 4x4 fp32 micro-kernel ----------------
__device__ __forceinline__ void mm4x4(const float4 a4, const float4 b4, float (&acc)[4][4]) {
    float av[4] = {a4.x, a4.y, a4.z, a4.w};
    float bv[4] = {b4.x, b4.y, b4.z, b4.w};
#pragma unroll
    for (int i = 0; i < 4; ++i)
#pragma unroll
        for (int j = 0; j < 4; ++j) acc[i][j] += av[i] * bv[j];
}

// ================= graph-learn stage 1: learned adjacency + gating =================
// new = relu(w1@w2^T - w2@w1^T + diag(beta)); gate = sigmoid(cw0*new + cw1*adj + cb)
// a = gate*new + (1-gate)*adj ; rs1 = rowsum(a)
__global__ __launch_bounds__(256)
void k_gl1(const float* __restrict__ adj, const float* __restrict__ beta,
           const float* __restrict__ w1, const float* __restrict__ w2,
           const float* __restrict__ cw, const float* __restrict__ cb,
           float* __restrict__ a_out, float* __restrict__ rs_out) {
    int i  = blockIdx.x;
    int br = blockIdx.y;
    __shared__ float w1r[DM], w2r[DM];
    __shared__ float red[256];
    int tid = threadIdx.x;
    const float* w1b = w1 + (size_t)br * N_NODES * DM;
    const float* w2b = w2 + (size_t)br * N_NODES * DM;
    if (tid < DM) {
        w1r[tid] = w1b[(size_t)i * DM + tid];
        w2r[tid] = w2b[(size_t)i * DM + tid];
    }
    __syncthreads();
    float aval = 0.f;
    if (tid < N_NODES) {
        int j = tid;
        const float4* w1j = (const float4*)(w1b + (size_t)j * DM);
        const float4* w2j = (const float4*)(w2b + (size_t)j * DM);
        float s1 = 0.f, s2 = 0.f;
#pragma unroll 6
        for (int cc = 0; cc < DM / 4; ++cc) {
            float4 u = w2j[cc];   // w2[j] chunk
            float4 v = w1j[cc];   // w1[j] chunk
            s1 += w1r[cc*4+0]*u.x + w1r[cc*4+1]*u.y + w1r[cc*4+2]*u.z + w1r[cc*4+3]*u.w;
            s2 += w2r[cc*4+0]*v.x + w2r[cc*4+1]*v.y + w2r[cc*4+2]*v.z + w2r[cc*4+3]*v.w;
        }
        float nv = s1 - s2 + (j == i ? beta[br * N_NODES + i] : 0.f);
        nv = fmaxf(nv, 0.f);
        float adjv = adj[(size_t)i * N_NODES + j];
        float z = cw[br*2+0] * nv + cw[br*2+1] * adjv + cb[br];
        float gate = 1.f / (1.f + __expf(-z));
        aval = gate * nv + (1.f - gate) * adjv;
        a_out[((size_t)br * N_NODES + i) * N_NODES + j] = aval;
    }
    red[tid] = aval;
    __syncthreads();
    for (int s = 128; s > 0; s >>= 1) {
        if (tid < s) red[tid] += red[tid + s];
        __syncthreads();
    }
    if (tid == 0) rs_out[br * N_NODES + i] = red[0];
}

// ================= graph-learn normalize passes =================
// mode 2: out = relu(d_i*in*d_j - eps), rs_out = rowsum
// mode 3: out = d_i*in*d_j (graph),     rs_out = rowsum
// mode 4: out = I - d_i*in*d_j (Laplacian), no reduce
__global__ __launch_bounds__(256)
void k_glnorm(const float* __restrict__ in, const float* __restrict__ rs,
              float* __restrict__ out, float* __restrict__ rs_out, int mode) {
    int i  = blockIdx.x;
    int br = blockIdx.y;
    __shared__ float red[256];
    int tid = threadIdx.x;
    float di = rsqrtf(rs[br * N_NODES + i]);
    float contrib = 0.f;
    if (tid < N_NODES) {
        float dj = rsqrtf(rs[br * N_NODES + tid]);
        float v = di * in[((size_t)br * N_NODES + i) * N_NODES + tid] * dj;
        float o;
        if (mode == 2)      { o = fmaxf(v - 0.5f / 170.f, 0.f); contrib = o; }
        else if (mode == 3) { o = v; contrib = v; }
        else                { o = (tid == i ? 1.f : 0.f) - v; }
        out[((size_t)br * N_NODES + i) * N_NODES + tid] = o;
    }
    if (mode != 4) {
        red[tid] = contrib;
        __syncthreads();
        for (int s = 128; s > 0; s >>= 1) {
            if (tid < s) red[tid] += red[tid + s];
            __syncthreads();
        }
        if (tid == 0) rs_out[br * N_NODES + i] = red[0];
    }
}

// ================= batched L-apply: Y[bt] = L @ X[bt]  (170x170 @ 170x120) =================
__global__ __launch_bounds__(256)
void k_lapply(const float* __restrict__ Lm, const float* __restrict__ X,
              float* __restrict__ Y) {
    __shared__ float As[16][68];   // [kk][row], padded stride 68 (16B-aligned float4 reads)
    __shared__ float Bs[16][64];   // [kk][col]
    int bt   = blockIdx.x;
    int tile = blockIdx.y;
    int n0 = (tile >> 1) * 64;
    int c0 = (tile & 1) * 64;
    int tid = threadIdx.x;
    int tx = tid & 15, ty = tid >> 4;
    float acc[4][4] = {{0.f}};
    const float* Xb = X + (size_t)bt * N_NODES * DM;
    for (int k0 = 0; k0 < N_NODES; k0 += 16) {
        int kmax = min(16, N_NODES - k0);
#pragma unroll
        for (int it = 0; it < 4; ++it) {
            int idx = tid + it * 256;
            int r = idx >> 4, kk = idx & 15;
            int n = n0 + r, k = k0 + kk;
            As[kk][r] = (n < N_NODES && k < N_NODES) ? Lm[(size_t)n * N_NODES + k] : 0.f;
        }
#pragma unroll
        for (int it = 0; it < 4; ++it) {
            int idx = tid + it * 256;
            int kk = idx >> 6, c = idx & 63;
            int k = k0 + kk, cc = c0 + c;
            Bs[kk][c] = (k < N_NODES && cc < DM) ? Xb[(size_t)k * DM + cc] : 0.f;
        }
        __syncthreads();
        if (kmax == 16) {
#pragma unroll
            for (int kk = 0; kk < 16; ++kk)
                mm4x4(*(const float4*)&As[kk][ty * 4], *(const float4*)&Bs[kk][tx * 4], acc);
        } else {
            for (int kk = 0; kk < kmax; ++kk)
                mm4x4(*(const float4*)&As[kk][ty * 4], *(const float4*)&Bs[kk][tx * 4], acc);
        }
        __syncthreads();
    }
#pragma unroll
    for (int i = 0; i < 4; ++i) {
        int n = n0 + ty * 4 + i;
        if (n < N_NODES) {
#pragma unroll
            for (int j = 0; j < 4; ++j) {
                int c = c0 + tx * 4 + j;
                if (c < DM) Y[((size_t)bt * N_NODES + n) * DM + c] = acc[i][j];
            }
        }
    }
}

// ================= Cheb combine: H = relu(X@(w0-w2) + Y1@w1 + 2*Y2@w2 + b) =================
__global__ __launch_bounds__(256)
void k_combine(const float* __restrict__ X, const float* __restrict__ Y1,
               const float* __restrict__ Y2, const float* __restrict__ W,
               const float* __restrict__ bias, float* __restrict__ H) {
    __shared__ float As[16][68];
    __shared__ float Bs[16][64];
    int r0 = blockIdx.x * 64;
    int o0 = blockIdx.y * 64;
    int tid = threadIdx.x;
    int tx = tid & 15, ty = tid >> 4;
    float acc[4][4] = {{0.f}};
    const float* srcs[3] = {X, Y1, Y2};
    for (int s = 0; s < 3; ++s) {
        const float* S = srcs[s];
        for (int k0 = 0; k0 < DM; k0 += 16) {
            int kmax = min(16, DM - k0);
#pragma unroll
            for (int it = 0; it < 4; ++it) {
                int idx = tid + it * 256;
                int r = idx >> 4, kk = idx & 15;
                int k = k0 + kk;
                As[kk][r] = (k < DM) ? S[(size_t)(r0 + r) * DM + k] : 0.f;
            }
#pragma unroll
            for (int it = 0; it < 4; ++it) {
                int idx = tid + it * 256;
                int kk = idx >> 6, o = idx & 63;
                int k = k0 + kk, oo = o0 + o;
                float v = 0.f;
                if (k < DM && oo < DM) {
                    if (s == 0)      v = W[(size_t)k * DM + oo] - W[2 * DM * DM + (size_t)k * DM + oo];
                    else if (s == 1) v = W[DM * DM + (size_t)k * DM + oo];
                    else             v = 2.f * W[2 * DM * DM + (size_t)k * DM + oo];
                }
                Bs[kk][o] = v;
            }
            __syncthreads();
            if (kmax == 16) {
#pragma unroll
                for (int kk = 0; kk < 16; ++kk)
                    mm4x4(*(const float4*)&As[kk][ty * 4], *(const float4*)&Bs[kk][tx * 4], acc);
            } else {
                for (int kk = 0; kk < kmax; ++kk)
                    mm4x4(*(const float4*)&As[kk][ty * 4], *(const float4*)&Bs[kk][tx * 4], acc);
            }
            __syncthreads();
        }
    }
#pragma unroll
    for (int i = 0; i < 4; ++i) {
        int r = r0 + ty * 4 + i;
#pragma unroll
        for (int j = 0; j < 4; ++j) {
            int o = o0 + tx * 4 + j;
            if (o < DM) H[(size_t)r * DM + o] = fmaxf(acc[i][j] + bias[o], 0.f);
        }
    }
}

// ================= attention + out-proj + residual + LN1, per (b,n) =================
__global__ __launch_bounds__(128)
void k_attn(const float* __restrict__ hq, const float* __restrict__ hk,
            const float* __restrict__ hv, const float* __restrict__ x,
            const float* __restrict__ out_w, const float* __restrict__ out_b,
            const float* __restrict__ g1, const float* __restrict__ be1,
            float* __restrict__ ln1out) {
    int n = blockIdx.x;
    int b = blockIdx.y;
    __shared__ float qs[SEQ * DM], ks[SEQ * DM], vs[SEQ * DM], os[SEQ * DM], rb[SEQ * DM];
    int tid = threadIdx.x;
    for (int idx = tid; idx < SEQ * DM; idx += 128) {
        int t = idx / DM, c = idx - t * DM;
        size_t g = ((size_t)(b * SEQ + t) * N_NODES + n) * DM + c;
        qs[idx] = hq[g]; ks[idx] = hk[g]; vs[idx] = hv[g];
    }
    __syncthreads();
    if (tid < 96) {                 // 8 heads x 12 query rows
        int h = tid & 7, tq = tid >> 3;
        float qr[15];
#pragma unroll
        for (int d = 0; d < 15; ++d) qr[d] = qs[tq * DM + h * 15 + d];
        float sc[SEQ];
        float mx = -1e30f;
#pragma unroll
        for (int tk = 0; tk < SEQ; ++tk) {
            float s = 0.f;
#pragma unroll
            for (int d = 0; d < 15; ++d) s += qr[d] * ks[tk * DM + h * 15 + d];
            s *= 0.25819888974716113f;   // 1/sqrt(15)
            sc[tk] = s;
            mx = fmaxf(mx, s);
        }
        float sum = 0.f;
#pragma unroll
        for (int tk = 0; tk < SEQ; ++tk) { sc[tk] = __expf(sc[tk] - mx); sum += sc[tk]; }
        float inv = 1.f / sum;
#pragma unroll
        for (int d = 0; d < 15; ++d) {
            float o = 0.f;
#pragma unroll
            for (int tk = 0; tk < SEQ; ++tk) o += sc[tk] * vs[tk * DM + h * 15 + d];
            os[tq * DM + h * 15 + d] = o * inv;
        }
    }
    __syncthreads();
    if (tid < DM) {                 // out-proj: each thread owns output column o
        int o = tid;
        float acc[SEQ];
#pragma unroll
        for (int t = 0; t < SEQ; ++t) acc[t] = 0.f;
        for (int c = 0; c < DM; ++c) {
            float wv = out_w[(size_t)c * DM + o];
#pragma unroll
            for (int t = 0; t < SEQ; ++t) acc[t] += os[t * DM + c] * wv;
        }
        float ob = out_b[o];
#pragma unroll
        for (int t = 0; t < SEQ; ++t) {
            size_t g = ((size_t)(b * SEQ + t) * N_NODES + n) * DM + o;
            rb[t * DM + o] = acc[t] + ob + x[g];
        }
    }
    __syncthreads();
    // LN1: wave w handles rows w*6 .. w*6+5; lane covers cols lane, lane+64
    int w = tid >> 6, lane = tid & 63;
    for (int rr = 0; rr < 6; ++rr) {
        int tq = w * 6 + rr;
        float v1 = rb[tq * DM + lane];
        float v2 = (lane + 64 < DM) ? rb[tq * DM + lane + 64] : 0.f;
        float s = v1 + v2, q = v1 * v1 + v2 * v2;
#pragma unroll
        for (int m = 1; m < 64; m <<= 1) {
            s += __shfl_xor(s, m);
            q += __shfl_xor(q, m);
        }
        float mean = s * (1.f / DM);
        float var  = q * (1.f / DM) - mean * mean;
        float rstd = rsqrtf(var + 1e-5f);
        size_t g = ((size_t)(b * SEQ + tq) * N_NODES + n) * DM;
        ln1out[g + lane] = (v1 - mean) * rstd * g1[lane] + be1[lane];
        if (lane + 64 < DM)
            ln1out[g + lane + 64] = (v2 - mean) * rstd * g1[lane + 64] + be1[lane + 64];
    }
}

// ================= fused FFN (120->2048->120) + residual + LN2 =================
__global__ __launch_bounds__(256)
void k_ffn(const float* __restrict__ Xin,
           const float* __restrict__ W1, const float* __restrict__ b1,
           const float* __restrict__ W2, const float* __restrict__ b2,
           const float* __restrict__ g2, const float* __restrict__ be2,
           float* __restrict__ Out) {
    __shared__ float XsT[DM][68];    // transposed X tile [c][r]
    __shared__ float HsT[64][68];    // transposed hidden chunk [j][r]
    __shared__ float BsA[16][64];    // W1 k-tile
    __shared__ float BsB[16][128];   // W2 k-tile (padded cols zeroed)
    int r0 = blockIdx.x * 64;
    int tid = threadIdx.x;
    int tx = tid & 15, ty = tid >> 4;
    for (int idx = tid; idx < 64 * DM; idx += 256) {
        int r = idx / DM, c = idx - r * DM;
        XsT[c][r] = Xin[(size_t)(r0 + r) * DM + c];
    }
    float accO[4][8];
#pragma unroll
    for (int i = 0; i < 4; ++i)
#pragma unroll
        for (int j = 0; j < 8; ++j) accO[i][j] = 0.f;
    __syncthreads();

    for (int hc = 0; hc < FF; hc += 64) {
        // ---- phase A: H[64r][64j] = relu(X @ W1[:, hc:hc+64] + b1) ----
        float acc[4][4] = {{0.f}};
        for (int k0 = 0; k0 < DM; k0 += 16) {
            int kmax = min(16, DM - k0);
#pragma unroll
            for (int it = 0; it < 4; ++it) {
                int idx = tid + it * 256;
                int kk = idx >> 6, j = idx & 63;
                int k = k0 + kk;
                BsA[kk][j] = (k < DM) ? W1[(size_t)k * FF + hc + j] : 0.f;
            }
            __syncthreads();
            if (kmax == 16) {
#pragma unroll
                for (int kk = 0; kk < 16; ++kk)
                    mm4x4(*(const float4*)&XsT[k0 + kk][ty * 4], *(const float4*)&BsA[kk][tx * 4], acc);
            } else {
                for (int kk = 0; kk < kmax; ++kk)
                    mm4x4(*(const float4*)&XsT[k0 + kk][ty * 4], *(const float4*)&BsA[kk][tx * 4], acc);
            }
            __syncthreads();
        }
#pragma unroll
        for (int j = 0; j < 4; ++j) {
            float bb = b1[hc + tx * 4 + j];
#pragma unroll
            for (int i = 0; i < 4; ++i)
                HsT[tx * 4 + j][ty * 4 + i] = fmaxf(acc[i][j] + bb, 0.f);
        }
        __syncthreads();
        // ---- phase B: O[64r][120o] += H @ W2[hc:hc+64, :] ----
#pragma unroll
        for (int j0 = 0; j0 < 64; j0 += 16) {
#pragma unroll
            for (int it = 0; it < 8; ++it) {
                int idx = tid + it * 256;
                int kk = idx >> 7, o = idx & 127;
                BsB[kk][o] = (o < DM) ? W2[(size_t)(hc + j0 + kk) * DM + o] : 0.f;
            }
            __syncthreads();
#pragma unroll
            for (int kk = 0; kk < 16; ++kk) {
                float4 a4  = *(const float4*)&HsT[j0 + kk][ty * 4];
                float4 blo = *(const float4*)&BsB[kk][tx * 8];
                float4 bhi = *(const float4*)&BsB[kk][tx * 8 + 4];
                float av[4] = {a4.x, a4.y, a4.z, a4.w};
                float bv[8] = {blo.x, blo.y, blo.z, blo.w, bhi.x, bhi.y, bhi.z, bhi.w};
#pragma unroll
                for (int i = 0; i < 4; ++i)
#pragma unroll
                    for (int j = 0; j < 8; ++j) accO[i][j] += av[i] * bv[j];
            }
            __syncthreads();
        }
    }
    // ---- epilogue: +b2, +residual(ln1 out == Xin), LN2, store ----
#pragma unroll
    for (int i = 0; i < 4; ++i) {
        int r = ty * 4 + i;
        float vals[8];
        float s = 0.f, q = 0.f;
#pragma unroll
        for (int j = 0; j < 8; ++j) {
            int o = tx * 8 + j;
            float v = 0.f;
            if (o < DM) v = accO[i][j] + b2[o] + XsT[o][r];
            vals[j] = v;
            s += v; q += v * v;
        }
#pragma unroll
        for (int m = 1; m < 16; m <<= 1) {   // reduce across the 16 tx lanes (row-owners)
            s += __shfl_xor(s, m);
            q += __shfl_xor(q, m);
        }
        float mean = s * (1.f / DM);
        float var  = q * (1.f / DM) - mean * mean;
        float rstd = rsqrtf(var + 1e-5f);
#pragma unroll
        for (int j = 0; j < 8; ++j) {
            int o = tx * 8 + j;
            if (o < DM)
                Out[(size_t)(r0 + r) * DM + o] = (vals[j] - mean) * rstd * g2[o] + be2[o];
        }
    }
}

// ================================ launch ================================
extern "C" void kernel_launch(void* const* d_in, const int* in_sizes, int n_in,
                              void* d_out, int out_size, void* d_ws, size_t ws_size,
                              hipStream_t stream) {
    const float* x      = (const float*)d_in[0];
    const float* adj    = (const float*)d_in[1];
    const float* gl_beta= (const float*)d_in[2];
    const float* gl_w1  = (const float*)d_in[3];
    const float* gl_w2  = (const float*)d_in[4];
    const float* gl_cw  = (const float*)d_in[5];
    const float* gl_cb  = (const float*)d_in[6];
    const float* cheb_w = (const float*)d_in[7];
    const float* cheb_b = (const float*)d_in[8];
    const float* out_w  = (const float*)d_in[9];
    const float* out_b  = (const float*)d_in[10];
    const float* ff_w1  = (const float*)d_in[11];
    const float* ff_b1  = (const float*)d_in[12];
    const float* ff_w2  = (const float*)d_in[13];
    const float* ff_b2  = (const float*)d_in[14];
    const float* ln1_g  = (const float*)d_in[15];
    const float* ln1_b  = (const float*)d_in[16];
    const float* ln2_g  = (const float*)d_in[17];
    const float* ln2_b  = (const float*)d_in[18];

    float* ws    = (float*)d_ws;
    float* a_buf = ws + OFF_A;
    float* a2buf = ws + OFF_A2;
    float* g_buf = ws + OFF_G;
    float* L_buf = ws + OFF_L;
    float* rs1   = ws + OFF_RS1;
    float* rs2   = ws + OFF_RS2;
    float* rs3   = ws + OFF_RS3;
    float* y1    = ws + OFF_Y1;
    float* y2    = ws + OFF_Y2;
    float* hq    = ws + OFF_HQ;
    float* hk    = ws + OFF_HK;
    float* hv    = ws + OFF_HV;
    float* ln1   = ws + OFF_LN1;

    // graph learning (3 branches)
    k_gl1   <<<dim3(N_NODES, 3), 256, 0, stream>>>(adj, gl_beta, gl_w1, gl_w2, gl_cw, gl_cb, a_buf, rs1);
    k_glnorm<<<dim3(N_NODES, 3), 256, 0, stream>>>(a_buf, rs1, a2buf, rs2, 2);
    k_glnorm<<<dim3(N_NODES, 3), 256, 0, stream>>>(a2buf, rs2, g_buf, rs3, 3);
    k_glnorm<<<dim3(N_NODES, 3), 256, 0, stream>>>(g_buf, rs3, L_buf, nullptr, 4);

    // Cheb conv per branch: y1 = L@x, y2 = L@y1, h = relu(x@(w0-w2)+y1@w1+2*y2@w2+b)
    float* hbuf[3] = {hq, hk, hv};
    for (int br = 0; br < 3; ++br) {
        const float* Lb = L_buf + (size_t)br * N_NODES * N_NODES;
        k_lapply<<<dim3(BT, 6), 256, 0, stream>>>(Lb, x,  y1);
        k_lapply<<<dim3(BT, 6), 256, 0, stream>>>(Lb, y1, y2);
        k_combine<<<dim3(ROWS / 64, 2), 256, 0, stream>>>(
            x, y1, y2, cheb_w + (size_t)br * 3 * DM * DM, cheb_b + br * DM, hbuf[br]);
    }

    // attention + out-proj + residual + LN1
    k_attn<<<dim3(N_NODES, BATCH), 128, 0, stream>>>(hq, hk, hv, x, out_w, out_b, ln1_g, ln1_b, ln1);

    // FFN + residual + LN2 -> output
    k_ffn<<<ROWS / 64, 256, 0, stream>>>(ln1, ff_w1, ff_b1, ff_w2, ff_b2, ln2_g, ln2_b, (float*)d_out);
}

// Round 2
// 1251.408 us; speedup vs baseline: 5.2481x; 5.2481x over previous
//
#include <hip/hip_runtime.h>
#include <cstddef>
#include <cstdint>

#define N_NODES 170
#define SEQ 12
#define BATCH 32
#define DM 120
#define BT (BATCH*SEQ)          // 384
#define ROWS (BT*N_NODES)       // 65280
#define FF 2048

typedef short short8 __attribute__((ext_vector_type(8)));
typedef float f32x4 __attribute__((ext_vector_type(4)));

// ---------------- workspace layout (in floats, 16-float aligned) ----------------
static constexpr size_t OFF_A   = 0;                       // 3*170*170 = 86700
static constexpr size_t OFF_A2  = 86704;
static constexpr size_t OFF_G   = 173408;
static constexpr size_t OFF_L   = 260112;
static constexpr size_t OFF_RS1 = 346816;                  // 3*170
static constexpr size_t OFF_RS2 = 347328;
static constexpr size_t OFF_RS3 = 347840;
static constexpr size_t OFF_Y1  = 348416;                  // 7,833,600 each below
static constexpr size_t OFF_Y2  = OFF_Y1 + 7833600;
static constexpr size_t OFF_HQ  = OFF_Y2 + 7833600;
static constexpr size_t OFF_HK  = OFF_HQ + 7833600;
static constexpr size_t OFF_HV  = OFF_HK + 7833600;
static constexpr size_t OFF_LN1 = OFF_HV + 7833600;
// total = 47,350,016 floats = 189.4 MB
// reuse: ln1bf (bf16, ROWS x 128 = 8,355,840 ushorts) lives in y1 region
//        W1T (2048x128 bf16) + W2R (32x128x64 bf16) live in y2 region

__device__ __forceinline__ unsigned short f2bf(float f) {
    unsigned int u = __float_as_uint(f);
    unsigned int r = (u + 0x7fffu + ((u >> 16) & 1u)) >> 16;
    return (unsigned short)r;
}

__device__ __forceinline__ void gld16(const void* g, void* l) {
    __builtin_amdgcn_global_load_lds(
        (const __attribute__((address_space(1))) void*)g,
        (__attribute__((address_space(3))) void*)l, 16, 0, 0);
}

// ---------------- 4x4 fp32 micro-kernel (kept for fp32 kernels) ----------------
__device__ __forceinline__ void mm4x4(const float4 a4, const float4 b4, float (&acc)[4][4]) {
    float av[4] = {a4.x, a4.y, a4.z, a4.w};
    float bv[4] = {b4.x, b4.y, b4.z, b4.w};
#pragma unroll
    for (int i = 0; i < 4; ++i)
#pragma unroll
        for (int j = 0; j < 4; ++j) acc[i][j] += av[i] * bv[j];
}

// ================= graph-learn stage 1 =================
__global__ __launch_bounds__(256)
void k_gl1(const float* __restrict__ adj, const float* __restrict__ beta,
           const float* __restrict__ w1, const float* __restrict__ w2,
           const float* __restrict__ cw, const float* __restrict__ cb,
           float* __restrict__ a_out, float* __restrict__ rs_out) {
    int i  = blockIdx.x;
    int br = blockIdx.y;
    __shared__ float w1r[DM], w2r[DM];
    __shared__ float red[256];
    int tid = threadIdx.x;
    const float* w1b = w1 + (size_t)br * N_NODES * DM;
    const float* w2b = w2 + (size_t)br * N_NODES * DM;
    if (tid < DM) {
        w1r[tid] = w1b[(size_t)i * DM + tid];
        w2r[tid] = w2b[(size_t)i * DM + tid];
    }
    __syncthreads();
    float aval = 0.f;
    if (tid < N_NODES) {
        int j = tid;
        const float4* w1j = (const float4*)(w1b + (size_t)j * DM);
        const float4* w2j = (const float4*)(w2b + (size_t)j * DM);
        float s1 = 0.f, s2 = 0.f;
#pragma unroll 6
        for (int cc = 0; cc < DM / 4; ++cc) {
            float4 u = w2j[cc];
            float4 v = w1j[cc];
            s1 += w1r[cc*4+0]*u.x + w1r[cc*4+1]*u.y + w1r[cc*4+2]*u.z + w1r[cc*4+3]*u.w;
            s2 += w2r[cc*4+0]*v.x + w2r[cc*4+1]*v.y + w2r[cc*4+2]*v.z + w2r[cc*4+3]*v.w;
        }
        float nv = s1 - s2 + (j == i ? beta[br * N_NODES + i] : 0.f);
        nv = fmaxf(nv, 0.f);
        float adjv = adj[(size_t)i * N_NODES + j];
        float z = cw[br*2+0] * nv + cw[br*2+1] * adjv + cb[br];
        float gate = 1.f / (1.f + __expf(-z));
        aval = gate * nv + (1.f - gate) * adjv;
        a_out[((size_t)br * N_NODES + i) * N_NODES + j] = aval;
    }
    red[tid] = aval;
    __syncthreads();
    for (int s = 128; s > 0; s >>= 1) {
        if (tid < s) red[tid] += red[tid + s];
        __syncthreads();
    }
    if (tid == 0) rs_out[br * N_NODES + i] = red[0];
}

// ================= graph-learn normalize passes =================
__global__ __launch_bounds__(256)
void k_glnorm(const float* __restrict__ in, const float* __restrict__ rs,
              float* __restrict__ out, float* __restrict__ rs_out, int mode) {
    int i  = blockIdx.x;
    int br = blockIdx.y;
    __shared__ float red[256];
    int tid = threadIdx.x;
    float di = rsqrtf(rs[br * N_NODES + i]);
    float contrib = 0.f;
    if (tid < N_NODES) {
        float dj = rsqrtf(rs[br * N_NODES + tid]);
        float v = di * in[((size_t)br * N_NODES + i) * N_NODES + tid] * dj;
        float o;
        if (mode == 2)      { o = fmaxf(v - 0.5f / 170.f, 0.f); contrib = o; }
        else if (mode == 3) { o = v; contrib = v; }
        else                { o = (tid == i ? 1.f : 0.f) - v; }
        out[((size_t)br * N_NODES + i) * N_NODES + tid] = o;
    }
    if (mode != 4) {
        red[tid] = contrib;
        __syncthreads();
        for (int s = 128; s > 0; s >>= 1) {
            if (tid < s) red[tid] += red[tid + s];
            __syncthreads();
        }
        if (tid == 0) rs_out[br * N_NODES + i] = red[0];
    }
}

// ================= batched L-apply =================
__global__ __launch_bounds__(256)
void k_lapply(const float* __restrict__ Lm, const float* __restrict__ X,
              float* __restrict__ Y) {
    __shared__ float As[16][68];
    __shared__ float Bs[16][64];
    int bt   = blockIdx.x;
    int tile = blockIdx.y;
    int n0 = (tile >> 1) * 64;
    int c0 = (tile & 1) * 64;
    int tid = threadIdx.x;
    int tx = tid & 15, ty = tid >> 4;
    float acc[4][4] = {{0.f}};
    const float* Xb = X + (size_t)bt * N_NODES * DM;
    for (int k0 = 0; k0 < N_NODES; k0 += 16) {
        int kmax = min(16, N_NODES - k0);
#pragma unroll
        for (int it = 0; it < 4; ++it) {
            int idx = tid + it * 256;
            int r = idx >> 4, kk = idx & 15;
            int n = n0 + r, k = k0 + kk;
            As[kk][r] = (n < N_NODES && k < N_NODES) ? Lm[(size_t)n * N_NODES + k] : 0.f;
        }
#pragma unroll
        for (int it = 0; it < 4; ++it) {
            int idx = tid + it * 256;
            int kk = idx >> 6, c = idx & 63;
            int k = k0 + kk, cc = c0 + c;
            Bs[kk][c] = (k < N_NODES && cc < DM) ? Xb[(size_t)k * DM + cc] : 0.f;
        }
        __syncthreads();
        if (kmax == 16) {
#pragma unroll
            for (int kk = 0; kk < 16; ++kk)
                mm4x4(*(const float4*)&As[kk][ty * 4], *(const float4*)&Bs[kk][tx * 4], acc);
        } else {
            for (int kk = 0; kk < kmax; ++kk)
                mm4x4(*(const float4*)&As[kk][ty * 4], *(const float4*)&Bs[kk][tx * 4], acc);
        }
        __syncthreads();
    }
#pragma unroll
    for (int i = 0; i < 4; ++i) {
        int n = n0 + ty * 4 + i;
        if (n < N_NODES) {
#pragma unroll
            for (int j = 0; j < 4; ++j) {
                int c = c0 + tx * 4 + j;
                if (c < DM) Y[((size_t)bt * N_NODES + n) * DM + c] = acc[i][j];
            }
        }
    }
}

// ================= Cheb combine =================
__global__ __launch_bounds__(256)
void k_combine(const float* __restrict__ X, const float* __restrict__ Y1,
               const float* __restrict__ Y2, const float* __restrict__ W,
               const float* __restrict__ bias, float* __restrict__ H) {
    __shared__ float As[16][68];
    __shared__ float Bs[16][64];
    int r0 = blockIdx.x * 64;
    int o0 = blockIdx.y * 64;
    int tid = threadIdx.x;
    int tx = tid & 15, ty = tid >> 4;
    float acc[4][4] = {{0.f}};
    const float* srcs[3] = {X, Y1, Y2};
    for (int s = 0; s < 3; ++s) {
        const float* S = srcs[s];
        for (int k0 = 0; k0 < DM; k0 += 16) {
            int kmax = min(16, DM - k0);
#pragma unroll
            for (int it = 0; it < 4; ++it) {
                int idx = tid + it * 256;
                int r = idx >> 4, kk = idx & 15;
                int k = k0 + kk;
                As[kk][r] = (k < DM) ? S[(size_t)(r0 + r) * DM + k] : 0.f;
            }
#pragma unroll
            for (int it = 0; it < 4; ++it) {
                int idx = tid + it * 256;
                int kk = idx >> 6, o = idx & 63;
                int k = k0 + kk, oo = o0 + o;
                float v = 0.f;
                if (k < DM && oo < DM) {
                    if (s == 0)      v = W[(size_t)k * DM + oo] - W[2 * DM * DM + (size_t)k * DM + oo];
                    else if (s == 1) v = W[DM * DM + (size_t)k * DM + oo];
                    else             v = 2.f * W[2 * DM * DM + (size_t)k * DM + oo];
                }
                Bs[kk][o] = v;
            }
            __syncthreads();
            if (kmax == 16) {
#pragma unroll
                for (int kk = 0; kk < 16; ++kk)
                    mm4x4(*(const float4*)&As[kk][ty * 4], *(const float4*)&Bs[kk][tx * 4], acc);
            } else {
                for (int kk = 0; kk < kmax; ++kk)
                    mm4x4(*(const float4*)&As[kk][ty * 4], *(const float4*)&Bs[kk][tx * 4], acc);
            }
            __syncthreads();
        }
    }
#pragma unroll
    for (int i = 0; i < 4; ++i) {
        int r = r0 + ty * 4 + i;
#pragma unroll
        for (int j = 0; j < 4; ++j) {
            int o = o0 + tx * 4 + j;
            if (o < DM) H[(size_t)r * DM + o] = fmaxf(acc[i][j] + bias[o], 0.f);
        }
    }
}

// ================= attention + out-proj + residual + LN1 =================
// writes ln1 (fp32, for FFN residual) AND ln1bf (bf16, K-padded to 128, for FFN MFMA)
__global__ __launch_bounds__(128)
void k_attn(const float* __restrict__ hq, const float* __restrict__ hk,
            const float* __restrict__ hv, const float* __restrict__ x,
            const float* __restrict__ out_w, const float* __restrict__ out_b,
            const float* __restrict__ g1, const float* __restrict__ be1,
            float* __restrict__ ln1out, unsigned short* __restrict__ ln1bf) {
    int n = blockIdx.x;
    int b = blockIdx.y;
    __shared__ float qs[SEQ * DM], ks[SEQ * DM], vs[SEQ * DM], os[SEQ * DM], rb[SEQ * DM];
    int tid = threadIdx.x;
    for (int idx = tid; idx < SEQ * DM; idx += 128) {
        int t = idx / DM, c = idx - t * DM;
        size_t g = ((size_t)(b * SEQ + t) * N_NODES + n) * DM + c;
        qs[idx] = hq[g]; ks[idx] = hk[g]; vs[idx] = hv[g];
    }
    __syncthreads();
    if (tid < 96) {
        int h = tid & 7, tq = tid >> 3;
        float qr[15];
#pragma unroll
        for (int d = 0; d < 15; ++d) qr[d] = qs[tq * DM + h * 15 + d];
        float sc[SEQ];
        float mx = -1e30f;
#pragma unroll
        for (int tk = 0; tk < SEQ; ++tk) {
            float s = 0.f;
#pragma unroll
            for (int d = 0; d < 15; ++d) s += qr[d] * ks[tk * DM + h * 15 + d];
            s *= 0.25819888974716113f;
            sc[tk] = s;
            mx = fmaxf(mx, s);
        }
        float sum = 0.f;
#pragma unroll
        for (int tk = 0; tk < SEQ; ++tk) { sc[tk] = __expf(sc[tk] - mx); sum += sc[tk]; }
        float inv = 1.f / sum;
#pragma unroll
        for (int d = 0; d < 15; ++d) {
            float o = 0.f;
#pragma unroll
            for (int tk = 0; tk < SEQ; ++tk) o += sc[tk] * vs[tk * DM + h * 15 + d];
            os[tq * DM + h * 15 + d] = o * inv;
        }
    }
    __syncthreads();
    if (tid < DM) {
        int o = tid;
        float acc[SEQ];
#pragma unroll
        for (int t = 0; t < SEQ; ++t) acc[t] = 0.f;
        for (int c = 0; c < DM; ++c) {
            float wv = out_w[(size_t)c * DM + o];
#pragma unroll
            for (int t = 0; t < SEQ; ++t) acc[t] += os[t * DM + c] * wv;
        }
        float ob = out_b[o];
#pragma unroll
        for (int t = 0; t < SEQ; ++t) {
            size_t g = ((size_t)(b * SEQ + t) * N_NODES + n) * DM + o;
            rb[t * DM + o] = acc[t] + ob + x[g];
        }
    }
    __syncthreads();
    int w = tid >> 6, lane = tid & 63;
    for (int rr = 0; rr < 6; ++rr) {
        int tq = w * 6 + rr;
        float v1 = rb[tq * DM + lane];
        float v2 = (lane + 64 < DM) ? rb[tq * DM + lane + 64] : 0.f;
        float s = v1 + v2, q = v1 * v1 + v2 * v2;
#pragma unroll
        for (int m = 1; m < 64; m <<= 1) {
            s += __shfl_xor(s, m);
            q += __shfl_xor(q, m);
        }
        float mean = s * (1.f / DM);
        float var  = q * (1.f / DM) - mean * mean;
        float rstd = rsqrtf(var + 1e-5f);
        size_t row = (size_t)(b * SEQ + tq) * N_NODES + n;
        size_t g = row * DM;
        float o1 = (v1 - mean) * rstd * g1[lane] + be1[lane];
        ln1out[g + lane] = o1;
        ln1bf[row * 128 + lane] = f2bf(o1);
        if (lane + 64 < DM) {
            float o2 = (v2 - mean) * rstd * g1[lane + 64] + be1[lane + 64];
            ln1out[g + lane + 64] = o2;
            ln1bf[row * 128 + lane + 64] = f2bf(o2);
        } else {
            ln1bf[row * 128 + lane + 64] = 0;   // zero K-pad cols 120..127
        }
    }
}

// ================= weight prep: bf16 transposes, pre-swizzled =================
// W1T[o][kpos], kpos: 16B-block b=k>>3 stored at b^(o&7)
__global__ __launch_bounds__(256)
void k_prep_w1(const float* __restrict__ W1, unsigned short* __restrict__ W1T) {
    int idx = blockIdx.x * 256 + threadIdx.x;      // 2048*128
    int o = idx >> 7, k = idx & 127;
    int b = k >> 3, ki = k & 7;
    int pos = (((b ^ (o & 7)) << 3) | ki);
    float v = (k < DM) ? W1[(size_t)k * FF + o] : 0.f;
    W1T[(size_t)o * 128 + pos] = f2bf(v);
}
// W2R[c][o][jpos]: chunk c, o=0..127 (pad >=120 zero), j'=0..63, block b=j'>>3 at b^(o&7)
__global__ __launch_bounds__(256)
void k_prep_w2(const float* __restrict__ W2, unsigned short* __restrict__ W2R) {
    int idx = blockIdx.x * 256 + threadIdx.x;      // 32*128*64
    int c = idx >> 13;
    int o = (idx >> 6) & 127;
    int j = idx & 63;
    int b = j >> 3, ji = j & 7;
    int pos = (((b ^ (o & 7)) << 3) | ji);
    float v = (o < DM) ? W2[(size_t)(c * 64 + j) * DM + o] : 0.f;
    W2R[((size_t)c << 13) + (o << 6) + pos] = f2bf(v);
}

// ================= MFMA FFN: O = LN2( X + relu(X@W1+b1)@W2 + b2 ) =================
// block: 64 rows; 4 waves. Phase A: wave w owns hidden col-tile w (16 cols), rows 0..63.
// Phase B: wave w owns O row-stripe w (16 rows), all 128 (pad) cols.
#define LDS_XW1A 0
#define LDS_W1B  8192
#define LDS_W2A  16384
#define LDS_W2B  24576
#define LDS_HS   32768      // 64 x 72 ushort
__global__ __launch_bounds__(256, 2)
void k_ffn_mfma(const unsigned short* __restrict__ Xbf,   // ln1bf [ROWS][128]
                const float* __restrict__ ln1,            // fp32 residual [ROWS][120]
                const unsigned short* __restrict__ W1T,   // [2048][128]
                const float* __restrict__ b1,
                const unsigned short* __restrict__ W2R,   // [32][128][64]
                const float* __restrict__ b2,
                const float* __restrict__ g2, const float* __restrict__ be2,
                float* __restrict__ Out) {
    __shared__ unsigned short lds[37376];
    const int tid  = threadIdx.x;
    const int w    = tid >> 6;
    const int lane = tid & 63;
    const int g    = lane >> 4;
    const int l15  = lane & 15;
    const int r0   = blockIdx.x * 64;

    // ---- prologue staging: Xs -> XW1A, W1 chunk0 -> W1B, W2 chunk0 -> W2A ----
    {
        const unsigned short* xsrc = Xbf + (size_t)r0 * 128;
#pragma unroll
        for (int it = 0; it < 4; ++it) {
            int seg = w * 4 + it;
            gld16(xsrc + seg * 512 + lane * 8, &lds[LDS_XW1A + seg * 512]);
        }
#pragma unroll
        for (int it = 0; it < 4; ++it) {
            int seg = w * 4 + it;
            gld16(W1T + seg * 512 + lane * 8, &lds[LDS_W1B + seg * 512]);
        }
#pragma unroll
        for (int it = 0; it < 4; ++it) {
            int seg = w * 4 + it;
            gld16(W2R + seg * 512 + lane * 8, &lds[LDS_W2A + seg * 512]);
        }
    }
    __syncthreads();

    // ---- preload X A-fragments: rows rt*16+l15, k = kk*32+g*8 (linear Xs) ----
    short8 xfrag[4][4];
#pragma unroll
    for (int rt = 0; rt < 4; ++rt)
#pragma unroll
        for (int kk = 0; kk < 4; ++kk)
            xfrag[rt][kk] = *(const short8*)&lds[LDS_XW1A + (rt * 16 + l15) * 128 + kk * 32 + g * 8];

    f32x4 accO[8] = {};
    const int mycolA = w * 16 + l15;          // phase-A hidden col
    const int myrowB = w * 16 + l15;          // phase-B A-frag row

    for (int t = 0; t < 32; ++t) {
        __syncthreads();   // staged chunk t resident (drains vmcnt); prev-iter LDS reads retired
        const int p = t & 1;
        // prefetch chunk t+1 into the other buffers
        if (t + 1 < 32) {
            const unsigned short* w1src = W1T + (size_t)(t + 1) * 8192;
            const unsigned short* w2src = W2R + (size_t)(t + 1) * 8192;
            unsigned short* w1dst = &lds[(p ? LDS_W1B : LDS_XW1A)];
            unsigned short* w2dst = &lds[(p ? LDS_W2A : LDS_W2B)];
#pragma unroll
            for (int it = 0; it < 4; ++it) {
                int seg = w * 4 + it;
                gld16(w1src + seg * 512 + lane * 8, w1dst + seg * 512);
                gld16(w2src + seg * 512 + lane * 8, w2dst + seg * 512);
            }
        }
        // ---- phase A: H = relu(X @ W1chunk + b1), wave computes cols w*16..+15 ----
        {
            const unsigned short* w1p = &lds[p ? LDS_XW1A : LDS_W1B];
            f32x4 accA[4] = {};
#pragma unroll
            for (int kk = 0; kk < 4; ++kk) {
                int b = kk * 4 + g;
                short8 bfrag = *(const short8*)&w1p[mycolA * 128 + ((b ^ (mycolA & 7)) << 3)];
#pragma unroll
                for (int rt = 0; rt < 4; ++rt)
                    accA[rt] = __builtin_amdgcn_mfma_f32_16x16x32_bf16(xfrag[rt][kk], bfrag, accA[rt], 0, 0, 0);
            }
            float b1v = b1[t * 64 + mycolA];
#pragma unroll
            for (int rt = 0; rt < 4; ++rt)
#pragma unroll
                for (int r = 0; r < 4; ++r) {
                    float v = fmaxf(accA[rt][r] + b1v, 0.f);
                    lds[LDS_HS + (rt * 16 + g * 4 + r) * 72 + mycolA] = f2bf(v);
                }
        }
        // mid barrier: lgkm-only (keep chunk t+1 prefetch in flight across phase B)
        asm volatile("s_waitcnt lgkmcnt(0)" ::: "memory");
        __builtin_amdgcn_sched_barrier(0);
        __builtin_amdgcn_s_barrier();
        // ---- phase B: accO += H @ W2chunk, wave owns rows w*16..+15, cols all ----
        {
            const unsigned short* w2p = &lds[p ? LDS_W2B : LDS_W2A];
#pragma unroll
            for (int kk = 0; kk < 2; ++kk) {
                short8 hfrag = *(const short8*)&lds[LDS_HS + myrowB * 72 + kk * 32 + g * 8];
                int b = kk * 4 + g;
#pragma unroll
                for (int c = 0; c < 8; ++c) {
                    int o = c * 16 + l15;
                    short8 w2frag = *(const short8*)&w2p[(o << 6) + ((b ^ (o & 7)) << 3)];
                    accO[c] = __builtin_amdgcn_mfma_f32_16x16x32_bf16(hfrag, w2frag, accO[c], 0, 0, 0);
                }
            }
        }
    }

    // ---- epilogue: +b2, +residual, LN2, store (wave w owns rows w*16..+15) ----
#pragma unroll
    for (int r = 0; r < 4; ++r) {
        int row = w * 16 + g * 4 + r;
        size_t grow = (size_t)(r0 + row);
        float vals[8];
        float s = 0.f, q = 0.f;
#pragma unroll
        for (int c = 0; c < 8; ++c) {
            int col = c * 16 + l15;
            float v = 0.f;
            if (col < DM) v = accO[c][r] + b2[col] + ln1[grow * DM + col];
            vals[c] = v;
            s += v; q += v * v;
        }
#pragma unroll
        for (int m = 1; m < 16; m <<= 1) {
            s += __shfl_xor(s, m);
            q += __shfl_xor(q, m);
        }
        float mean = s * (1.f / DM);
        float var  = q * (1.f / DM) - mean * mean;
        float rstd = rsqrtf(var + 1e-5f);
#pragma unroll
        for (int c = 0; c < 8; ++c) {
            int col = c * 16 + l15;
            if (col < DM)
                Out[grow * DM + col] = (vals[c] - mean) * rstd * g2[col] + be2[col];
        }
    }
}

// ================================ launch ================================
extern "C" void kernel_launch(void* const* d_in, const int* in_sizes, int n_in,
                              void* d_out, int out_size, void* d_ws, size_t ws_size,
                              hipStream_t stream) {
    const float* x      = (const float*)d_in[0];
    const float* adj    = (const float*)d_in[1];
    const float* gl_beta= (const float*)d_in[2];
    const float* gl_w1  = (const float*)d_in[3];
    const float* gl_w2  = (const float*)d_in[4];
    const float* gl_cw  = (const float*)d_in[5];
    const float* gl_cb  = (const float*)d_in[6];
    const float* cheb_w = (const float*)d_in[7];
    const float* cheb_b = (const float*)d_in[8];
    const float* out_w  = (const float*)d_in[9];
    const float* out_b  = (const float*)d_in[10];
    const float* ff_w1  = (const float*)d_in[11];
    const float* ff_b1  = (const float*)d_in[12];
    const float* ff_w2  = (const float*)d_in[13];
    const float* ff_b2  = (const float*)d_in[14];
    const float* ln1_g  = (const float*)d_in[15];
    const float* ln1_b  = (const float*)d_in[16];
    const float* ln2_g  = (const float*)d_in[17];
    const float* ln2_b  = (const float*)d_in[18];

    float* ws    = (float*)d_ws;
    float* a_buf = ws + OFF_A;
    float* a2buf = ws + OFF_A2;
    float* g_buf = ws + OFF_G;
    float* L_buf = ws + OFF_L;
    float* rs1   = ws + OFF_RS1;
    float* rs2   = ws + OFF_RS2;
    float* rs3   = ws + OFF_RS3;
    float* y1    = ws + OFF_Y1;
    float* y2    = ws + OFF_Y2;
    float* hq    = ws + OFF_HQ;
    float* hk    = ws + OFF_HK;
    float* hv    = ws + OFF_HV;
    float* ln1   = ws + OFF_LN1;
    // bf16 buffers carved out of dead y1/y2 regions (post-combine)
    unsigned short* ln1bf = (unsigned short*)y1;                 // ROWS*128 ushorts
    unsigned short* W1T   = (unsigned short*)y2;                 // 2048*128
    unsigned short* W2R   = (unsigned short*)(y2 + 131072);      // 32*128*64

    // graph learning (3 branches)
    k_gl1   <<<dim3(N_NODES, 3), 256, 0, stream>>>(adj, gl_beta, gl_w1, gl_w2, gl_cw, gl_cb, a_buf, rs1);
    k_glnorm<<<dim3(N_NODES, 3), 256, 0, stream>>>(a_buf, rs1, a2buf, rs2, 2);
    k_glnorm<<<dim3(N_NODES, 3), 256, 0, stream>>>(a2buf, rs2, g_buf, rs3, 3);
    k_glnorm<<<dim3(N_NODES, 3), 256, 0, stream>>>(g_buf, rs3, L_buf, nullptr, 4);

    // Cheb conv per branch
    float* hbuf[3] = {hq, hk, hv};
    for (int br = 0; br < 3; ++br) {
        const float* Lb = L_buf + (size_t)br * N_NODES * N_NODES;
        k_lapply<<<dim3(BT, 6), 256, 0, stream>>>(Lb, x,  y1);
        k_lapply<<<dim3(BT, 6), 256, 0, stream>>>(Lb, y1, y2);
        k_combine<<<dim3(ROWS / 64, 2), 256, 0, stream>>>(
            x, y1, y2, cheb_w + (size_t)br * 3 * DM * DM, cheb_b + br * DM, hbuf[br]);
    }

    // FFN weight prep (y1/y2 regions are dead from here on)
    k_prep_w1<<<(2048 * 128) / 256, 256, 0, stream>>>(ff_w1, W1T);
    k_prep_w2<<<(32 * 128 * 64) / 256, 256, 0, stream>>>(ff_w2, W2R);

    // attention + out-proj + residual + LN1 (writes fp32 + bf16)
    k_attn<<<dim3(N_NODES, BATCH), 128, 0, stream>>>(hq, hk, hv, x, out_w, out_b, ln1_g, ln1_b, ln1, ln1bf);

    // MFMA FFN + residual + LN2 -> output
    k_ffn_mfma<<<ROWS / 64, 256, 0, stream>>>(ln1bf, ln1, W1T, ff_b1, W2R, ff_b2, ln2_g, ln2_b, (float*)d_out);
}

// Round 3
// 596.944 us; speedup vs baseline: 11.0018x; 2.0964x over previous
//
#include <hip/hip_runtime.h>
#include <cstddef>
#include <cstdint>

#define N_NODES 170
#define SEQ 12
#define BATCH 32
#define DM 120
#define BT (BATCH*SEQ)          // 384
#define ROWS (BT*N_NODES)       // 65280
#define FF 2048

typedef short short8 __attribute__((ext_vector_type(8)));
typedef float f32x4 __attribute__((ext_vector_type(4)));

// ---------------- workspace layout (in floats) ----------------
static constexpr size_t OFF_A   = 0;                       // 3*170*170
static constexpr size_t OFF_A2  = 86704;
static constexpr size_t OFF_G   = 173408;
static constexpr size_t OFF_L   = 260112;                  // L_bf bf16 3*31808 ush = 47712 fl (fits 86704)
static constexpr size_t OFF_RS1 = 346816;
static constexpr size_t OFF_RS2 = 347328;
static constexpr size_t OFF_RS3 = 347840;
static constexpr size_t OFF_XT  = 348416;                  // xT bf16 [384][128][176] = 4,325,376 fl
static constexpr size_t OFF_Y1T = 4673792;                 // y1T bf16 (single-branch scratch) 4,325,376 fl
static constexpr size_t OFF_XNM = 8999168;                 // x_nm bf16 [ROWS][128] = 4,177,920 fl
static constexpr size_t OFF_Y12 = 13177088;                // y12_nm bf16 3 x [ROWS][256] = 25,067,520 fl
static constexpr size_t OFF_BC  = 38244608;                // Bc bf16 3*128*384 = 73,728 fl
static constexpr size_t OFF_HV  = 38318336;                // hv bf16 [ROWS][128] = 4,177,920 fl
// END = 42,496,256 fl = 170.0 MB  (<= 189.4 MB proven available)
// aliases: hq -> OFF_XT, hk -> OFF_Y1T, ln1bf -> y12[0], ln1 -> y12[1], W1T/W2R -> y12[2]

__device__ __forceinline__ unsigned short f2bf(float f) {
    unsigned int u = __float_as_uint(f);
    unsigned int r = (u + 0x7fffu + ((u >> 16) & 1u)) >> 16;
    return (unsigned short)r;
}
__device__ __forceinline__ float bf2f(unsigned short h) {
    return __uint_as_float(((unsigned int)h) << 16);
}
__device__ __forceinline__ void gld16(const void* g, void* l) {
    __builtin_amdgcn_global_load_lds(
        (const __attribute__((address_space(1))) void*)g,
        (__attribute__((address_space(3))) void*)l, 16, 0, 0);
}
__device__ __forceinline__ uint4 pack8(const unsigned short v[8]) {
    uint4 q;
    q.x = (unsigned)v[0] | ((unsigned)v[1] << 16);
    q.y = (unsigned)v[2] | ((unsigned)v[3] << 16);
    q.z = (unsigned)v[4] | ((unsigned)v[5] << 16);
    q.w = (unsigned)v[6] | ((unsigned)v[7] << 16);
    return q;
}

// ================= graph-learn stage 1 =================
__global__ __launch_bounds__(256)
void k_gl1(const float* __restrict__ adj, const float* __restrict__ beta,
           const float* __restrict__ w1, const float* __restrict__ w2,
           const float* __restrict__ cw, const float* __restrict__ cb,
           float* __restrict__ a_out, float* __restrict__ rs_out) {
    int i  = blockIdx.x;
    int br = blockIdx.y;
    __shared__ float w1r[DM], w2r[DM];
    __shared__ float red[256];
    int tid = threadIdx.x;
    const float* w1b = w1 + (size_t)br * N_NODES * DM;
    const float* w2b = w2 + (size_t)br * N_NODES * DM;
    if (tid < DM) {
        w1r[tid] = w1b[(size_t)i * DM + tid];
        w2r[tid] = w2b[(size_t)i * DM + tid];
    }
    __syncthreads();
    float aval = 0.f;
    if (tid < N_NODES) {
        int j = tid;
        const float4* w1j = (const float4*)(w1b + (size_t)j * DM);
        const float4* w2j = (const float4*)(w2b + (size_t)j * DM);
        float s1 = 0.f, s2 = 0.f;
#pragma unroll 6
        for (int cc = 0; cc < DM / 4; ++cc) {
            float4 u = w2j[cc];
            float4 v = w1j[cc];
            s1 += w1r[cc*4+0]*u.x + w1r[cc*4+1]*u.y + w1r[cc*4+2]*u.z + w1r[cc*4+3]*u.w;
            s2 += w2r[cc*4+0]*v.x + w2r[cc*4+1]*v.y + w2r[cc*4+2]*v.z + w2r[cc*4+3]*v.w;
        }
        float nv = s1 - s2 + (j == i ? beta[br * N_NODES + i] : 0.f);
        nv = fmaxf(nv, 0.f);
        float adjv = adj[(size_t)i * N_NODES + j];
        float z = cw[br*2+0] * nv + cw[br*2+1] * adjv + cb[br];
        float gate = 1.f / (1.f + __expf(-z));
        aval = gate * nv + (1.f - gate) * adjv;
        a_out[((size_t)br * N_NODES + i) * N_NODES + j] = aval;
    }
    red[tid] = aval;
    __syncthreads();
    for (int s = 128; s > 0; s >>= 1) {
        if (tid < s) red[tid] += red[tid + s];
        __syncthreads();
    }
    if (tid == 0) rs_out[br * N_NODES + i] = red[0];
}

// ================= graph-learn normalize passes (modes 2,3) =================
__global__ __launch_bounds__(256)
void k_glnorm(const float* __restrict__ in, const float* __restrict__ rs,
              float* __restrict__ out, float* __restrict__ rs_out, int mode) {
    int i  = blockIdx.x;
    int br = blockIdx.y;
    __shared__ float red[256];
    int tid = threadIdx.x;
    float di = rsqrtf(rs[br * N_NODES + i]);
    float contrib = 0.f;
    if (tid < N_NODES) {
        float dj = rsqrtf(rs[br * N_NODES + tid]);
        float v = di * in[((size_t)br * N_NODES + i) * N_NODES + tid] * dj;
        float o;
        if (mode == 2) { o = fmaxf(v - 0.5f / 170.f, 0.f); contrib = o; }
        else           { o = v; contrib = v; }
        out[((size_t)br * N_NODES + i) * N_NODES + tid] = o;
    }
    red[tid] = contrib;
    __syncthreads();
    for (int s = 128; s > 0; s >>= 1) {
        if (tid < s) red[tid] += red[tid + s];
        __syncthreads();
    }
    if (tid == 0) rs_out[br * N_NODES + i] = red[0];
}

// ================= L prep: L_bf[br][176][180] bf16, zero-padded =================
__global__ __launch_bounds__(192)
void k_prep_L(const float* __restrict__ g_buf, const float* __restrict__ rs3,
              unsigned short* __restrict__ Lbf) {
    int i  = blockIdx.x;   // 0..175
    int br = blockIdx.y;
    int j  = threadIdx.x;
    if (j >= 180) return;
    float v = 0.f;
    if (i < N_NODES && j < N_NODES) {
        float di = rsqrtf(rs3[br * N_NODES + i]);
        float dj = rsqrtf(rs3[br * N_NODES + j]);
        float gg = g_buf[((size_t)br * N_NODES + i) * N_NODES + j];
        v = (i == j ? 1.f : 0.f) - di * gg * dj;
    }
    Lbf[(size_t)br * 31808 + i * 180 + j] = f2bf(v);
}

// ================= x prep: xT (channel-major bf16) + x_nm (node-major bf16, swizzled) =================
__global__ __launch_bounds__(256)
void k_prep_x(const float* __restrict__ x, unsigned short* __restrict__ xT,
              unsigned short* __restrict__ xnm) {
    __shared__ unsigned short LX[170 * 121 + 8];
    int bt = blockIdx.x, tid = threadIdx.x;
    const float* xb = x + (size_t)bt * N_NODES * DM;
    for (int u = tid; u < 170 * 30; u += 256) {
        int nn = u / 30, cq = u - nn * 30;
        float4 v = *(const float4*)&xb[nn * 120 + cq * 4];
        LX[nn * 121 + cq * 4 + 0] = f2bf(v.x);
        LX[nn * 121 + cq * 4 + 1] = f2bf(v.y);
        LX[nn * 121 + cq * 4 + 2] = f2bf(v.z);
        LX[nn * 121 + cq * 4 + 3] = f2bf(v.w);
    }
    __syncthreads();
    // xT[bt][c][176]
    for (int u = tid; u < 128 * 22; u += 256) {
        int c = u / 22, mb = u - c * 22;
        unsigned short vals[8];
#pragma unroll
        for (int i2 = 0; i2 < 8; ++i2) {
            int m = mb * 8 + i2;
            vals[i2] = (c < 120 && m < 170) ? LX[m * 121 + c] : (unsigned short)0;
        }
        *(uint4*)&xT[(size_t)bt * 22528 + c * 176 + mb * 8] = pack8(vals);
    }
    // x_nm[(bt*170+n)][128] with 16B-block swizzle b' = (b&8)|((b&7)^(row&7))
    for (int u = tid; u < 170 * 16; u += 256) {
        int nn = u >> 4, b = u & 15;
        unsigned int row = bt * 170 + nn;
        unsigned short vals[8];
#pragma unroll
        for (int i2 = 0; i2 < 8; ++i2) {
            int c = b * 8 + i2;
            vals[i2] = (c < 120) ? LX[nn * 121 + c] : (unsigned short)0;
        }
        int bs = (b & 8) | ((b & 7) ^ (row & 7));
        *(uint4*)&xnm[(size_t)row * 128 + bs * 8] = pack8(vals);
    }
}

// ================= Cheb weight prep: Bc[br][o=128][c=384] = [W0-W2 | W1 | 2W2]^T bf16 =================
__global__ __launch_bounds__(256)
void k_prep_Bc(const float* __restrict__ cheb_w, unsigned short* __restrict__ Bc) {
    int idx = blockIdx.x * 256 + threadIdx.x;   // 3*128*384
    int br  = idx / 49152;
    int rem = idx - br * 49152;
    int o   = rem / 384;
    int c   = rem - o * 384;
    float v = 0.f;
    if (o < 120) {
        int part = c >> 7, cc = c & 127;
        if (cc < 120) {
            const float* Wb = cheb_w + (size_t)br * 3 * 14400;
            if (part == 0)      v = Wb[cc * 120 + o] - Wb[2 * 14400 + cc * 120 + o];
            else if (part == 1) v = Wb[14400 + cc * 120 + o];
            else                v = 2.f * Wb[2 * 14400 + cc * 120 + o];
        }
    }
    Bc[idx] = f2bf(v);
}

// ================= T-form L-apply: Y^T = X^T @ L^T  (per bt) =================
// A = Asrc[c][m] (channel-major bf16, stride 176), B = L row-major in LDS (stride 180).
// writes yT (channel-major, optional) and ynm (node-major swizzled, at coloff)
__global__ __launch_bounds__(256)
void k_lapplyT(const unsigned short* __restrict__ Asrc_base,
               const unsigned short* __restrict__ Lg,
               unsigned short* __restrict__ yT,
               unsigned short* __restrict__ ynm, int coloff) {
    __shared__ __attribute__((aligned(16))) unsigned short Llds[31744]; // 63488 B
    const int tid = threadIdx.x, w = tid >> 6, lane = tid & 63;
    const int g = lane >> 4, l15 = lane & 15;
    const int bt = blockIdx.x;
    const unsigned short* Asrc = Asrc_base + (size_t)bt * 22528;
    // stage L (63360 B linear)
    const char* Lgb = (const char*)Lg;
    char* Lldsb = (char*)Llds;
#pragma unroll
    for (int it = 0; it < 16; ++it) {
        int q = it * 4 + w;
        if (q * 1024 < 63360)
            gld16(Lgb + q * 1024 + lane * 16, Lldsb + q * 1024);
    }
    // A-frags from global: wave w owns c-tiles 2w, 2w+1
    short8 af[2][6];
#pragma unroll
    for (int ct2 = 0; ct2 < 2; ++ct2) {
        int c = (w * 2 + ct2) * 16 + l15;
#pragma unroll
        for (int kb = 0; kb < 6; ++kb) {
            if (kb < 5) af[ct2][kb] = *(const short8*)&Asrc[c * 176 + kb * 32 + g * 8];
            else {
                short8 z = {};
                af[ct2][kb] = (g < 2) ? *(const short8*)&Asrc[c * 176 + 160 + g * 8] : z;
            }
        }
    }
    __syncthreads();
    f32x4 acc[2][11];
#pragma unroll
    for (int a = 0; a < 2; ++a)
#pragma unroll
        for (int b = 0; b < 11; ++b) acc[a][b] = (f32x4){0.f, 0.f, 0.f, 0.f};
#pragma unroll
    for (int nt = 0; nt < 11; ++nt) {
        short8 bf[6];
        int rb = (nt * 16 + l15) * 180;
#pragma unroll
        for (int kb = 0; kb < 6; ++kb) {
            if (kb < 5) bf[kb] = *(const short8*)&Llds[rb + kb * 32 + g * 8];
            else {
                short8 z = {};
                bf[kb] = (g < 2) ? *(const short8*)&Llds[rb + 160 + g * 8] : z;
            }
        }
#pragma unroll
        for (int kb = 0; kb < 6; ++kb)
#pragma unroll
            for (int ct2 = 0; ct2 < 2; ++ct2)
                acc[ct2][nt] = __builtin_amdgcn_mfma_f32_16x16x32_bf16(af[ct2][kb], bf[kb], acc[ct2][nt], 0, 0, 0);
    }
    // stores
#pragma unroll
    for (int nt = 0; nt < 11; ++nt) {
        int nn = nt * 16 + l15;
#pragma unroll
        for (int ct2 = 0; ct2 < 2; ++ct2) {
            int base_c = (w * 2 + ct2) * 16 + g * 4;
            if (yT) {
#pragma unroll
                for (int r = 0; r < 4; ++r) {
                    int c = base_c + r;
                    float v = (c < 120 && nn < 170) ? acc[ct2][nt][r] : 0.f;
                    yT[(size_t)bt * 22528 + c * 176 + nn] = f2bf(v);
                }
            }
            if (nn < 170) {
                unsigned int row = bt * 170 + nn;
                unsigned short u[4];
#pragma unroll
                for (int r = 0; r < 4; ++r)
                    u[r] = (base_c + r < 120) ? f2bf(acc[ct2][nt][r]) : (unsigned short)0;
                int bc  = coloff + base_c;
                int blk = bc >> 3;
                int bsw = (blk & 24) | ((blk & 7) ^ (row & 7));
                uint2 pk;
                pk.x = (unsigned)u[0] | ((unsigned)u[1] << 16);
                pk.y = (unsigned)u[2] | ((unsigned)u[3] << 16);
                *(uint2*)&ynm[(size_t)row * 256 + bsw * 8 + (bc & 7)] = pk;
            }
        }
    }
}

// ================= MFMA Cheb combine: H = relu([x|y1|y2] @ Bc^T + b) -> bf16 =================
__global__ __launch_bounds__(256)
void k_combine_mfma(const unsigned short* __restrict__ xnm,
                    const unsigned short* __restrict__ ynm,
                    const unsigned short* __restrict__ Bc,
                    const float* __restrict__ bias,
                    unsigned short* __restrict__ Hout) {
    __shared__ __attribute__((aligned(16))) unsigned short AsX[64 * 128];
    __shared__ __attribute__((aligned(16))) unsigned short AsY[64 * 256];
    const int tid = threadIdx.x, w = tid >> 6, lane = tid & 63;
    const int g = lane >> 4, l15 = lane & 15;
    const int r0 = blockIdx.x * 64;
#pragma unroll
    for (int it = 0; it < 4; ++it) {
        int q = w * 4 + it;
        gld16(xnm + (size_t)r0 * 128 + q * 512 + lane * 8, &AsX[q * 512]);
    }
#pragma unroll
    for (int it = 0; it < 8; ++it) {
        int q = w * 8 + it;
        gld16(ynm + (size_t)r0 * 256 + q * 512 + lane * 8, &AsY[q * 512]);
    }
    __syncthreads();
    const int lr = w * 16 + l15;     // A row within tile (wave w owns rows w*16..+15)
    short8 af[12];
#pragma unroll
    for (int kb = 0; kb < 4; ++kb) {
        int b = kb * 4 + g;
        int bs = (b & 8) | ((b & 7) ^ (lr & 7));
        af[kb] = *(const short8*)&AsX[lr * 128 + bs * 8];
    }
#pragma unroll
    for (int kb = 4; kb < 12; ++kb) {
        int b = (kb - 4) * 4 + g;
        int bs = (b & 24) | ((b & 7) ^ (lr & 7));
        af[kb] = *(const short8*)&AsY[lr * 256 + bs * 8];
    }
    f32x4 acc[8];
#pragma unroll
    for (int c = 0; c < 8; ++c) acc[c] = (f32x4){0.f, 0.f, 0.f, 0.f};
    short8 bfA[8], bfB[8];
#pragma unroll
    for (int c = 0; c < 8; ++c)
        bfA[c] = *(const short8*)&Bc[(size_t)(c * 16 + l15) * 384 + g * 8];
#pragma unroll
    for (int kb = 0; kb < 12; ++kb) {
        if (kb + 1 < 12) {
#pragma unroll
            for (int c = 0; c < 8; ++c) {
                short8 v = *(const short8*)&Bc[(size_t)(c * 16 + l15) * 384 + (kb + 1) * 32 + g * 8];
                if (kb & 1) bfA[c] = v; else bfB[c] = v;
            }
        }
#pragma unroll
        for (int c = 0; c < 8; ++c)
            acc[c] = __builtin_amdgcn_mfma_f32_16x16x32_bf16(af[kb], (kb & 1) ? bfB[c] : bfA[c], acc[c], 0, 0, 0);
    }
#pragma unroll
    for (int c = 0; c < 8; ++c) {
        int o = c * 16 + l15;
        float bv = (o < 120) ? bias[o] : 0.f;
#pragma unroll
        for (int r = 0; r < 4; ++r) {
            int row = r0 + w * 16 + g * 4 + r;
            float v = (o < 120) ? fmaxf(acc[c][r] + bv, 0.f) : 0.f;
            Hout[(size_t)row * 128 + o] = f2bf(v);
        }
    }
}

// ================= attention + out-proj + residual + LN1 (bf16 h inputs) =================
__global__ __launch_bounds__(128)
void k_attn(const unsigned short* __restrict__ hq, const unsigned short* __restrict__ hk,
            const unsigned short* __restrict__ hv, const float* __restrict__ x,
            const float* __restrict__ out_w, const float* __restrict__ out_b,
            const float* __restrict__ g1, const float* __restrict__ be1,
            float* __restrict__ ln1out, unsigned short* __restrict__ ln1bf) {
    int n = blockIdx.x;
    int b = blockIdx.y;
    __shared__ float qs[SEQ * DM], ks[SEQ * DM], vs[SEQ * DM], os[SEQ * DM], rb[SEQ * DM];
    int tid = threadIdx.x;
    for (int idx = tid; idx < SEQ * 15; idx += 128) {
        int t = idx / 15, seg = idx - t * 15;
        size_t row = ((size_t)(b * SEQ + t) * N_NODES + n);
        short8 vq = *(const short8*)&hq[row * 128 + seg * 8];
        short8 vk = *(const short8*)&hk[row * 128 + seg * 8];
        short8 vv = *(const short8*)&hv[row * 128 + seg * 8];
#pragma unroll
        for (int j = 0; j < 8; ++j) {
            int c = seg * 8 + j;
            qs[t * DM + c] = bf2f((unsigned short)vq[j]);
            ks[t * DM + c] = bf2f((unsigned short)vk[j]);
            vs[t * DM + c] = bf2f((unsigned short)vv[j]);
        }
    }
    __syncthreads();
    if (tid < 96) {
        int h = tid & 7, tq = tid >> 3;
        float qr[15];
#pragma unroll
        for (int d = 0; d < 15; ++d) qr[d] = qs[tq * DM + h * 15 + d];
        float sc[SEQ];
        float mx = -1e30f;
#pragma unroll
        for (int tk = 0; tk < SEQ; ++tk) {
            float s = 0.f;
#pragma unroll
            for (int d = 0; d < 15; ++d) s += qr[d] * ks[tk * DM + h * 15 + d];
            s *= 0.25819888974716113f;
            sc[tk] = s;
            mx = fmaxf(mx, s);
        }
        float sum = 0.f;
#pragma unroll
        for (int tk = 0; tk < SEQ; ++tk) { sc[tk] = __expf(sc[tk] - mx); sum += sc[tk]; }
        float inv = 1.f / sum;
#pragma unroll
        for (int d = 0; d < 15; ++d) {
            float o = 0.f;
#pragma unroll
            for (int tk = 0; tk < SEQ; ++tk) o += sc[tk] * vs[tk * DM + h * 15 + d];
            os[tq * DM + h * 15 + d] = o * inv;
        }
    }
    __syncthreads();
    if (tid < DM) {
        int o = tid;
        float acc[SEQ];
#pragma unroll
        for (int t = 0; t < SEQ; ++t) acc[t] = 0.f;
        for (int c = 0; c < DM; ++c) {
            float wv = out_w[(size_t)c * DM + o];
#pragma unroll
            for (int t = 0; t < SEQ; ++t) acc[t] += os[t * DM + c] * wv;
        }
        float ob = out_b[o];
#pragma unroll
        for (int t = 0; t < SEQ; ++t) {
            size_t gg = ((size_t)(b * SEQ + t) * N_NODES + n) * DM + o;
            rb[t * DM + o] = acc[t] + ob + x[gg];
        }
    }
    __syncthreads();
    int w = tid >> 6, lane = tid & 63;
    for (int rr = 0; rr < 6; ++rr) {
        int tq = w * 6 + rr;
        float v1 = rb[tq * DM + lane];
        float v2 = (lane + 64 < DM) ? rb[tq * DM + lane + 64] : 0.f;
        float s = v1 + v2, q = v1 * v1 + v2 * v2;
#pragma unroll
        for (int m = 1; m < 64; m <<= 1) {
            s += __shfl_xor(s, m);
            q += __shfl_xor(q, m);
        }
        float mean = s * (1.f / DM);
        float var  = q * (1.f / DM) - mean * mean;
        float rstd = rsqrtf(var + 1e-5f);
        size_t row = (size_t)(b * SEQ + tq) * N_NODES + n;
        size_t gg = row * DM;
        float o1 = (v1 - mean) * rstd * g1[lane] + be1[lane];
        ln1out[gg + lane] = o1;
        ln1bf[row * 128 + lane] = f2bf(o1);
        if (lane + 64 < DM) {
            float o2 = (v2 - mean) * rstd * g1[lane + 64] + be1[lane + 64];
            ln1out[gg + lane + 64] = o2;
            ln1bf[row * 128 + lane + 64] = f2bf(o2);
        } else {
            ln1bf[row * 128 + lane + 64] = 0;
        }
    }
}

// ================= FFN weight prep =================
__global__ __launch_bounds__(256)
void k_prep_w1(const float* __restrict__ W1, unsigned short* __restrict__ W1T) {
    int idx = blockIdx.x * 256 + threadIdx.x;
    int o = idx >> 7, k = idx & 127;
    int b = k >> 3, ki = k & 7;
    int pos = (((b ^ (o & 7)) << 3) | ki);
    float v = (k < DM) ? W1[(size_t)k * FF + o] : 0.f;
    W1T[(size_t)o * 128 + pos] = f2bf(v);
}
__global__ __launch_bounds__(256)
void k_prep_w2(const float* __restrict__ W2, unsigned short* __restrict__ W2R) {
    int idx = blockIdx.x * 256 + threadIdx.x;
    int c = idx >> 13;
    int o = (idx >> 6) & 127;
    int j = idx & 63;
    int b = j >> 3, ji = j & 7;
    int pos = (((b ^ (o & 7)) << 3) | ji);
    float v = (o < DM) ? W2[(size_t)(c * 64 + j) * DM + o] : 0.f;
    W2R[((size_t)c << 13) + (o << 6) + pos] = f2bf(v);
}

// ================= MFMA FFN: O = LN2( X + relu(X@W1+b1)@W2 + b2 ) =================
#define LDS_XW1A 0
#define LDS_W1B  8192
#define LDS_W2A  16384
#define LDS_W2B  24576
#define LDS_HS   32768
__global__ __launch_bounds__(256, 2)
void k_ffn_mfma(const unsigned short* __restrict__ Xbf,
                const float* __restrict__ ln1,
                const unsigned short* __restrict__ W1T,
                const float* __restrict__ b1,
                const unsigned short* __restrict__ W2R,
                const float* __restrict__ b2,
                const float* __restrict__ g2, const float* __restrict__ be2,
                float* __restrict__ Out) {
    __shared__ unsigned short lds[37376];
    const int tid  = threadIdx.x;
    const int w    = tid >> 6;
    const int lane = tid & 63;
    const int g    = lane >> 4;
    const int l15  = lane & 15;
    const int r0   = blockIdx.x * 64;
    {
        const unsigned short* xsrc = Xbf + (size_t)r0 * 128;
#pragma unroll
        for (int it = 0; it < 4; ++it) {
            int seg = w * 4 + it;
            gld16(xsrc + seg * 512 + lane * 8, &lds[LDS_XW1A + seg * 512]);
        }
#pragma unroll
        for (int it = 0; it < 4; ++it) {
            int seg = w * 4 + it;
            gld16(W1T + seg * 512 + lane * 8, &lds[LDS_W1B + seg * 512]);
        }
#pragma unroll
        for (int it = 0; it < 4; ++it) {
            int seg = w * 4 + it;
            gld16(W2R + seg * 512 + lane * 8, &lds[LDS_W2A + seg * 512]);
        }
    }
    __syncthreads();
    short8 xfrag[4][4];
#pragma unroll
    for (int rt = 0; rt < 4; ++rt)
#pragma unroll
        for (int kk = 0; kk < 4; ++kk)
            xfrag[rt][kk] = *(const short8*)&lds[LDS_XW1A + (rt * 16 + l15) * 128 + kk * 32 + g * 8];

    f32x4 accO[8] = {};
    const int mycolA = w * 16 + l15;
    const int myrowB = w * 16 + l15;

    for (int t = 0; t < 32; ++t) {
        __syncthreads();
        const int p = t & 1;
        if (t + 1 < 32) {
            const unsigned short* w1src = W1T + (size_t)(t + 1) * 8192;
            const unsigned short* w2src = W2R + (size_t)(t + 1) * 8192;
            unsigned short* w1dst = &lds[(p ? LDS_W1B : LDS_XW1A)];
            unsigned short* w2dst = &lds[(p ? LDS_W2A : LDS_W2B)];
#pragma unroll
            for (int it = 0; it < 4; ++it) {
                int seg = w * 4 + it;
                gld16(w1src + seg * 512 + lane * 8, w1dst + seg * 512);
                gld16(w2src + seg * 512 + lane * 8, w2dst + seg * 512);
            }
        }
        {
            const unsigned short* w1p = &lds[p ? LDS_XW1A : LDS_W1B];
            f32x4 accA[4] = {};
#pragma unroll
            for (int kk = 0; kk < 4; ++kk) {
                int b = kk * 4 + g;
                short8 bfrag = *(const short8*)&w1p[mycolA * 128 + ((b ^ (mycolA & 7)) << 3)];
#pragma unroll
                for (int rt = 0; rt < 4; ++rt)
                    accA[rt] = __builtin_amdgcn_mfma_f32_16x16x32_bf16(xfrag[rt][kk], bfrag, accA[rt], 0, 0, 0);
            }
            float b1v = b1[t * 64 + mycolA];
#pragma unroll
            for (int rt = 0; rt < 4; ++rt)
#pragma unroll
                for (int r = 0; r < 4; ++r) {
                    float v = fmaxf(accA[rt][r] + b1v, 0.f);
                    lds[LDS_HS + (rt * 16 + g * 4 + r) * 72 + mycolA] = f2bf(v);
                }
        }
        asm volatile("s_waitcnt lgkmcnt(0)" ::: "memory");
        __builtin_amdgcn_sched_barrier(0);
        __builtin_amdgcn_s_barrier();
        {
            const unsigned short* w2p = &lds[p ? LDS_W2B : LDS_W2A];
#pragma unroll
            for (int kk = 0; kk < 2; ++kk) {
                short8 hfrag = *(const short8*)&lds[LDS_HS + myrowB * 72 + kk * 32 + g * 8];
                int b = kk * 4 + g;
#pragma unroll
                for (int c = 0; c < 8; ++c) {
                    int o = c * 16 + l15;
                    short8 w2frag = *(const short8*)&w2p[(o << 6) + ((b ^ (o & 7)) << 3)];
                    accO[c] = __builtin_amdgcn_mfma_f32_16x16x32_bf16(hfrag, w2frag, accO[c], 0, 0, 0);
                }
            }
        }
    }
#pragma unroll
    for (int r = 0; r < 4; ++r) {
        int row = w * 16 + g * 4 + r;
        size_t grow = (size_t)(r0 + row);
        float vals[8];
        float s = 0.f, q = 0.f;
#pragma unroll
        for (int c = 0; c < 8; ++c) {
            int col = c * 16 + l15;
            float v = 0.f;
            if (col < DM) v = accO[c][r] + b2[col] + ln1[grow * DM + col];
            vals[c] = v;
            s += v; q += v * v;
        }
#pragma unroll
        for (int m = 1; m < 16; m <<= 1) {
            s += __shfl_xor(s, m);
            q += __shfl_xor(q, m);
        }
        float mean = s * (1.f / DM);
        float var  = q * (1.f / DM) - mean * mean;
        float rstd = rsqrtf(var + 1e-5f);
#pragma unroll
        for (int c = 0; c < 8; ++c) {
            int col = c * 16 + l15;
            if (col < DM)
                Out[grow * DM + col] = (vals[c] - mean) * rstd * g2[col] + be2[col];
        }
    }
}

// ================================ launch ================================
extern "C" void kernel_launch(void* const* d_in, const int* in_sizes, int n_in,
                              void* d_out, int out_size, void* d_ws, size_t ws_size,
                              hipStream_t stream) {
    const float* x      = (const float*)d_in[0];
    const float* adj    = (const float*)d_in[1];
    const float* gl_beta= (const float*)d_in[2];
    const float* gl_w1  = (const float*)d_in[3];
    const float* gl_w2  = (const float*)d_in[4];
    const float* gl_cw  = (const float*)d_in[5];
    const float* gl_cb  = (const float*)d_in[6];
    const float* cheb_w = (const float*)d_in[7];
    const float* cheb_b = (const float*)d_in[8];
    const float* out_w  = (const float*)d_in[9];
    const float* out_b  = (const float*)d_in[10];
    const float* ff_w1  = (const float*)d_in[11];
    const float* ff_b1  = (const float*)d_in[12];
    const float* ff_w2  = (const float*)d_in[13];
    const float* ff_b2  = (const float*)d_in[14];
    const float* ln1_g  = (const float*)d_in[15];
    const float* ln1_b  = (const float*)d_in[16];
    const float* ln2_g  = (const float*)d_in[17];
    const float* ln2_b  = (const float*)d_in[18];

    float* ws    = (float*)d_ws;
    float* a_buf = ws + OFF_A;
    float* a2buf = ws + OFF_A2;
    float* g_buf = ws + OFF_G;
    float* rs1   = ws + OFF_RS1;
    float* rs2   = ws + OFF_RS2;
    float* rs3   = ws + OFF_RS3;
    unsigned short* L_bf = (unsigned short*)(ws + OFF_L);
    unsigned short* xT   = (unsigned short*)(ws + OFF_XT);
    unsigned short* y1T  = (unsigned short*)(ws + OFF_Y1T);
    unsigned short* xnm  = (unsigned short*)(ws + OFF_XNM);
    unsigned short* Bc   = (unsigned short*)(ws + OFF_BC);
    // h outputs (bf16), aliased onto dead regions
    unsigned short* hq   = (unsigned short*)(ws + OFF_XT);
    unsigned short* hk   = (unsigned short*)(ws + OFF_Y1T);
    unsigned short* hv   = (unsigned short*)(ws + OFF_HV);
    unsigned short* ln1bf= (unsigned short*)(ws + OFF_Y12);
    float*          ln1  = ws + OFF_Y12 + 8355840;
    unsigned short* W1T  = (unsigned short*)(ws + OFF_Y12 + 2 * 8355840);
    unsigned short* W2R  = W1T + 262144;

    // graph learning
    k_gl1   <<<dim3(N_NODES, 3), 256, 0, stream>>>(adj, gl_beta, gl_w1, gl_w2, gl_cw, gl_cb, a_buf, rs1);
    k_glnorm<<<dim3(N_NODES, 3), 256, 0, stream>>>(a_buf, rs1, a2buf, rs2, 2);
    k_glnorm<<<dim3(N_NODES, 3), 256, 0, stream>>>(a2buf, rs2, g_buf, rs3, 3);
    k_prep_L<<<dim3(176, 3), 192, 0, stream>>>(g_buf, rs3, L_bf);

    // preps
    k_prep_x <<<BT, 256, 0, stream>>>(x, xT, xnm);
    k_prep_Bc<<<576, 256, 0, stream>>>(cheb_w, Bc);

    // Cheb: per branch T-form L-applies
    for (int br = 0; br < 3; ++br) {
        const unsigned short* Lb = L_bf + (size_t)br * 31808;
        unsigned short* ynm = (unsigned short*)(ws + OFF_Y12) + (size_t)br * 16711680;
        k_lapplyT<<<BT, 256, 0, stream>>>(xT,  Lb, y1T,    ynm, 0);
        k_lapplyT<<<BT, 256, 0, stream>>>(y1T, Lb, nullptr, ynm, 128);
    }
    // Cheb combine (MFMA) -> hq/hk/hv bf16
    unsigned short* hout[3] = {hq, hk, hv};
    for (int br = 0; br < 3; ++br) {
        const unsigned short* ynm = (const unsigned short*)(ws + OFF_Y12) + (size_t)br * 16711680;
        k_combine_mfma<<<ROWS / 64, 256, 0, stream>>>(xnm, ynm, Bc + (size_t)br * 49152,
                                                      cheb_b + br * DM, hout[br]);
    }

    // FFN weight prep (y12[2] region dead after combine br=2)
    k_prep_w1<<<(2048 * 128) / 256, 256, 0, stream>>>(ff_w1, W1T);
    k_prep_w2<<<(32 * 128 * 64) / 256, 256, 0, stream>>>(ff_w2, W2R);

    // attention + out-proj + residual + LN1
    k_attn<<<dim3(N_NODES, BATCH), 128, 0, stream>>>(hq, hk, hv, x, out_w, out_b, ln1_g, ln1_b, ln1, ln1bf);

    // FFN + residual + LN2 -> output
    k_ffn_mfma<<<ROWS / 64, 256, 0, stream>>>(ln1bf, ln1, W1T, ff_b1, W2R, ff_b2, ln2_g, ln2_b, (float*)d_out);
}

// Round 4
// 551.842 us; speedup vs baseline: 11.9010x; 1.0817x over previous
//
#include <hip/hip_runtime.h>
#include <cstddef>
#include <cstdint>

#define N_NODES 170
#define SEQ 12
#define BATCH 32
#define DM 120
#define BT (BATCH*SEQ)          // 384
#define ROWS (BT*N_NODES)       // 65280
#define FF 2048

typedef short short8 __attribute__((ext_vector_type(8)));
typedef float f32x4 __attribute__((ext_vector_type(4)));

// ---------------- workspace layout (floats) ----------------
// smalls
static constexpr size_t OFF_A    = 0;          // 86,704
static constexpr size_t OFF_G    = 86704;      // a2 / g reuse: need both -> two buffers
static constexpr size_t OFF_A2   = 173408;
static constexpr size_t OFF_L    = 260112;     // L_bf bf16 3*31808 ush = 47,712 fl
static constexpr size_t OFF_RS1  = 307824;
static constexpr size_t OFF_RS2  = 308336;
static constexpr size_t OFF_RS3  = 308848;
// bigs
static constexpr size_t OFF_XT   = 309360;                     // 4,325,376
static constexpr size_t OFF_XNM  = OFF_XT  + 4325376;          // 4,177,920   -> 8,812,656
static constexpr size_t OFF_Y1T  = OFF_XNM + 4177920;          // 3x4,325,376 -> 21,788,784
static constexpr size_t OFF_YNM  = OFF_Y1T + 3*4325376;        // 3x8,355,840 -> 46,856,304? no:
// OFF_YNM = 21,788,784 ; + 25,067,520 = 46,856,304
static constexpr size_t OFF_BC   = OFF_YNM + 3*8355840;        // 73,728 -> end 46,930,032 (< 47,350,016 proven)
// aliases (regions dead at time of use):
static constexpr size_t OFF_HQ   = OFF_XT;                     // after hop1 (xT dead)
static constexpr size_t OFF_HK   = OFF_Y1T;                    // after hop2 (y1T dead)
static constexpr size_t OFF_HV   = OFF_Y1T + 4177920;          // y1T region is 12.97MF, fits hk+hv
static constexpr size_t OFF_W1T  = OFF_YNM;                    // after combine (ynm dead)
static constexpr size_t OFF_W2R  = OFF_W1T + 131072;
static constexpr size_t OFF_ONM  = OFF_W2R + 131072;           // 4,177,920
static constexpr size_t OFF_LN1  = OFF_ONM + 4177920;          // 7,833,600
static constexpr size_t OFF_LN1B = OFF_LN1 + 7833600;          // 4,177,920
static constexpr size_t OFF_OWT  = OFF_LN1B + 4177920;         // 8,192 -> end 46,425,264 (inside ynm region ✓)

static constexpr size_t Y1T_BR_STRIDE = 8650752;   // ushorts per branch (4,325,376 fl)
static constexpr size_t YNM_BR_STRIDE = 16711680;  // ushorts per branch

__device__ __forceinline__ unsigned short f2bf(float f) {
    unsigned int u = __float_as_uint(f);
    unsigned int r = (u + 0x7fffu + ((u >> 16) & 1u)) >> 16;
    return (unsigned short)r;
}
__device__ __forceinline__ float bf2f(unsigned short h) {
    return __uint_as_float(((unsigned int)h) << 16);
}
__device__ __forceinline__ void gld16(const void* g, void* l) {
    __builtin_amdgcn_global_load_lds(
        (const __attribute__((address_space(1))) void*)g,
        (__attribute__((address_space(3))) void*)l, 16, 0, 0);
}
__device__ __forceinline__ uint4 pack8(const unsigned short v[8]) {
    uint4 q;
    q.x = (unsigned)v[0] | ((unsigned)v[1] << 16);
    q.y = (unsigned)v[2] | ((unsigned)v[3] << 16);
    q.z = (unsigned)v[4] | ((unsigned)v[5] << 16);
    q.w = (unsigned)v[6] | ((unsigned)v[7] << 16);
    return q;
}

// ================= graph-learn stage 1 =================
__global__ __launch_bounds__(256)
void k_gl1(const float* __restrict__ adj, const float* __restrict__ beta,
           const float* __restrict__ w1, const float* __restrict__ w2,
           const float* __restrict__ cw, const float* __restrict__ cb,
           float* __restrict__ a_out, float* __restrict__ rs_out) {
    int i  = blockIdx.x;
    int br = blockIdx.y;
    __shared__ float w1r[DM], w2r[DM];
    __shared__ float red[256];
    int tid = threadIdx.x;
    const float* w1b = w1 + (size_t)br * N_NODES * DM;
    const float* w2b = w2 + (size_t)br * N_NODES * DM;
    if (tid < DM) {
        w1r[tid] = w1b[(size_t)i * DM + tid];
        w2r[tid] = w2b[(size_t)i * DM + tid];
    }
    __syncthreads();
    float aval = 0.f;
    if (tid < N_NODES) {
        int j = tid;
        const float4* w1j = (const float4*)(w1b + (size_t)j * DM);
        const float4* w2j = (const float4*)(w2b + (size_t)j * DM);
        float s1 = 0.f, s2 = 0.f;
#pragma unroll 6
        for (int cc = 0; cc < DM / 4; ++cc) {
            float4 u = w2j[cc];
            float4 v = w1j[cc];
            s1 += w1r[cc*4+0]*u.x + w1r[cc*4+1]*u.y + w1r[cc*4+2]*u.z + w1r[cc*4+3]*u.w;
            s2 += w2r[cc*4+0]*v.x + w2r[cc*4+1]*v.y + w2r[cc*4+2]*v.z + w2r[cc*4+3]*v.w;
        }
        float nv = s1 - s2 + (j == i ? beta[br * N_NODES + i] : 0.f);
        nv = fmaxf(nv, 0.f);
        float adjv = adj[(size_t)i * N_NODES + j];
        float z = cw[br*2+0] * nv + cw[br*2+1] * adjv + cb[br];
        float gate = 1.f / (1.f + __expf(-z));
        aval = gate * nv + (1.f - gate) * adjv;
        a_out[((size_t)br * N_NODES + i) * N_NODES + j] = aval;
    }
    red[tid] = aval;
    __syncthreads();
    for (int s = 128; s > 0; s >>= 1) {
        if (tid < s) red[tid] += red[tid + s];
        __syncthreads();
    }
    if (tid == 0) rs_out[br * N_NODES + i] = red[0];
}

// ================= graph-learn normalize passes (modes 2,3) =================
__global__ __launch_bounds__(256)
void k_glnorm(const float* __restrict__ in, const float* __restrict__ rs,
              float* __restrict__ out, float* __restrict__ rs_out, int mode) {
    int i  = blockIdx.x;
    int br = blockIdx.y;
    __shared__ float red[256];
    int tid = threadIdx.x;
    float di = rsqrtf(rs[br * N_NODES + i]);
    float contrib = 0.f;
    if (tid < N_NODES) {
        float dj = rsqrtf(rs[br * N_NODES + tid]);
        float v = di * in[((size_t)br * N_NODES + i) * N_NODES + tid] * dj;
        float o;
        if (mode == 2) { o = fmaxf(v - 0.5f / 170.f, 0.f); contrib = o; }
        else           { o = v; contrib = v; }
        out[((size_t)br * N_NODES + i) * N_NODES + tid] = o;
    }
    red[tid] = contrib;
    __syncthreads();
    for (int s = 128; s > 0; s >>= 1) {
        if (tid < s) red[tid] += red[tid + s];
        __syncthreads();
    }
    if (tid == 0) rs_out[br * N_NODES + i] = red[0];
}

// ================= L prep: L_bf[br][176][180] bf16, zero-padded =================
__global__ __launch_bounds__(192)
void k_prep_L(const float* __restrict__ g_buf, const float* __restrict__ rs3,
              unsigned short* __restrict__ Lbf) {
    int i  = blockIdx.x;   // 0..175
    int br = blockIdx.y;
    int j  = threadIdx.x;
    if (j >= 180) return;
    float v = 0.f;
    if (i < N_NODES && j < N_NODES) {
        float di = rsqrtf(rs3[br * N_NODES + i]);
        float dj = rsqrtf(rs3[br * N_NODES + j]);
        float gg = g_buf[((size_t)br * N_NODES + i) * N_NODES + j];
        v = (i == j ? 1.f : 0.f) - di * gg * dj;
    }
    Lbf[(size_t)br * 31808 + i * 180 + j] = f2bf(v);
}

// ================= x prep: xT (channel-major) + x_nm (node-major swizzled) =================
__global__ __launch_bounds__(256)
void k_prep_x(const float* __restrict__ x, unsigned short* __restrict__ xT,
              unsigned short* __restrict__ xnm) {
    __shared__ unsigned short LX[170 * 121 + 8];
    int bt = blockIdx.x, tid = threadIdx.x;
    const float* xb = x + (size_t)bt * N_NODES * DM;
    for (int u = tid; u < 170 * 30; u += 256) {
        int nn = u / 30, cq = u - nn * 30;
        float4 v = *(const float4*)&xb[nn * 120 + cq * 4];
        LX[nn * 121 + cq * 4 + 0] = f2bf(v.x);
        LX[nn * 121 + cq * 4 + 1] = f2bf(v.y);
        LX[nn * 121 + cq * 4 + 2] = f2bf(v.z);
        LX[nn * 121 + cq * 4 + 3] = f2bf(v.w);
    }
    __syncthreads();
    for (int u = tid; u < 128 * 22; u += 256) {
        int c = u / 22, mb = u - c * 22;
        unsigned short vals[8];
#pragma unroll
        for (int i2 = 0; i2 < 8; ++i2) {
            int m = mb * 8 + i2;
            vals[i2] = (c < 120 && m < 170) ? LX[m * 121 + c] : (unsigned short)0;
        }
        *(uint4*)&xT[(size_t)bt * 22528 + c * 176 + mb * 8] = pack8(vals);
    }
    for (int u = tid; u < 170 * 16; u += 256) {
        int nn = u >> 4, b = u & 15;
        unsigned int row = bt * 170 + nn;
        unsigned short vals[8];
#pragma unroll
        for (int i2 = 0; i2 < 8; ++i2) {
            int c = b * 8 + i2;
            vals[i2] = (c < 120) ? LX[nn * 121 + c] : (unsigned short)0;
        }
        int bs = (b & 8) | ((b & 7) ^ (row & 7));
        *(uint4*)&xnm[(size_t)row * 128 + bs * 8] = pack8(vals);
    }
}

// ================= Cheb weight prep: Bc[br][o=128][c=384] =================
__global__ __launch_bounds__(256)
void k_prep_Bc(const float* __restrict__ cheb_w, unsigned short* __restrict__ Bc) {
    int idx = blockIdx.x * 256 + threadIdx.x;
    int br  = idx / 49152;
    int rem = idx - br * 49152;
    int o   = rem / 384;
    int c   = rem - o * 384;
    float v = 0.f;
    if (o < 120) {
        int part = c >> 7, cc = c & 127;
        if (cc < 120) {
            const float* Wb = cheb_w + (size_t)br * 3 * 14400;
            if (part == 0)      v = Wb[cc * 120 + o] - Wb[2 * 14400 + cc * 120 + o];
            else if (part == 1) v = Wb[14400 + cc * 120 + o];
            else                v = 2.f * Wb[2 * 14400 + cc * 120 + o];
        }
    }
    Bc[idx] = f2bf(v);
}

// ================= T-form L-apply (merged branches, kb-outer ILP) =================
__global__ __launch_bounds__(256)
void k_lapplyT(const unsigned short* __restrict__ Asrc_base, size_t asrc_br_stride,
               const unsigned short* __restrict__ Lg_base,
               unsigned short* __restrict__ yT_base,
               unsigned short* __restrict__ ynm_base, int coloff) {
    __shared__ __attribute__((aligned(16))) unsigned short Llds[31744];
    const int tid = threadIdx.x, w = tid >> 6, lane = tid & 63;
    const int g = lane >> 4, l15 = lane & 15;
    const int bt = blockIdx.x, br = blockIdx.y;
    const unsigned short* Asrc = Asrc_base + (size_t)br * asrc_br_stride + (size_t)bt * 22528;
    const unsigned short* Lg   = Lg_base + (size_t)br * 31808;
    unsigned short* ynm = ynm_base + (size_t)br * YNM_BR_STRIDE;
    unsigned short* yT  = yT_base ? yT_base + (size_t)br * Y1T_BR_STRIDE + (size_t)bt * 22528 : nullptr;
    const char* Lgb = (const char*)Lg;
    char* Lldsb = (char*)Llds;
#pragma unroll
    for (int it = 0; it < 16; ++it) {
        int q = it * 4 + w;
        if (q * 1024 < 63360)
            gld16(Lgb + q * 1024 + lane * 16, Lldsb + q * 1024);
    }
    short8 af[2][6];
#pragma unroll
    for (int ct2 = 0; ct2 < 2; ++ct2) {
        int c = (w * 2 + ct2) * 16 + l15;
#pragma unroll
        for (int kb = 0; kb < 6; ++kb) {
            if (kb < 5) af[ct2][kb] = *(const short8*)&Asrc[c * 176 + kb * 32 + g * 8];
            else {
                short8 z = {};
                af[ct2][kb] = (g < 2) ? *(const short8*)&Asrc[c * 176 + 160 + g * 8] : z;
            }
        }
    }
    __syncthreads();
    f32x4 acc[2][11];
#pragma unroll
    for (int a = 0; a < 2; ++a)
#pragma unroll
        for (int b = 0; b < 11; ++b) acc[a][b] = (f32x4){0.f, 0.f, 0.f, 0.f};
#pragma unroll
    for (int kb = 0; kb < 6; ++kb) {
#pragma unroll
        for (int nt = 0; nt < 11; ++nt) {
            short8 bf;
            int rb = (nt * 16 + l15) * 180;
            if (kb < 5) bf = *(const short8*)&Llds[rb + kb * 32 + g * 8];
            else {
                short8 z = {};
                bf = (g < 2) ? *(const short8*)&Llds[rb + 160 + g * 8] : z;
            }
            acc[0][nt] = __builtin_amdgcn_mfma_f32_16x16x32_bf16(af[0][kb], bf, acc[0][nt], 0, 0, 0);
            acc[1][nt] = __builtin_amdgcn_mfma_f32_16x16x32_bf16(af[1][kb], bf, acc[1][nt], 0, 0, 0);
        }
    }
#pragma unroll
    for (int nt = 0; nt < 11; ++nt) {
        int nn = nt * 16 + l15;
#pragma unroll
        for (int ct2 = 0; ct2 < 2; ++ct2) {
            int base_c = (w * 2 + ct2) * 16 + g * 4;
            if (yT) {
#pragma unroll
                for (int r = 0; r < 4; ++r) {
                    int c = base_c + r;
                    float v = (c < 120 && nn < 170) ? acc[ct2][nt][r] : 0.f;
                    yT[c * 176 + nn] = f2bf(v);
                }
            }
            if (nn < 170) {
                unsigned int row = bt * 170 + nn;
                unsigned short u[4];
#pragma unroll
                for (int r = 0; r < 4; ++r)
                    u[r] = (base_c + r < 120) ? f2bf(acc[ct2][nt][r]) : (unsigned short)0;
                int bc  = coloff + base_c;
                int blk = bc >> 3;
                int bsw = (blk & 24) | ((blk & 7) ^ (row & 7));
                uint2 pk;
                pk.x = (unsigned)u[0] | ((unsigned)u[1] << 16);
                pk.y = (unsigned)u[2] | ((unsigned)u[3] << 16);
                *(uint2*)&ynm[(size_t)row * 256 + bsw * 8 + (bc & 7)] = pk;
            }
        }
    }
}

// ================= MFMA Cheb combine (merged branches) =================
__global__ __launch_bounds__(256)
void k_combine_mfma(const unsigned short* __restrict__ xnm,
                    const unsigned short* __restrict__ ynm_base,
                    const unsigned short* __restrict__ Bc_base,
                    const float* __restrict__ bias_base,
                    unsigned short* __restrict__ h0,
                    unsigned short* __restrict__ h1,
                    unsigned short* __restrict__ h2) {
    __shared__ __attribute__((aligned(16))) unsigned short AsX[64 * 128];
    __shared__ __attribute__((aligned(16))) unsigned short AsY[64 * 256];
    const int tid = threadIdx.x, w = tid >> 6, lane = tid & 63;
    const int g = lane >> 4, l15 = lane & 15;
    const int r0 = blockIdx.x * 64;
    const int br = blockIdx.y;
    const unsigned short* ynm = ynm_base + (size_t)br * YNM_BR_STRIDE;
    const unsigned short* Bc  = Bc_base + (size_t)br * 49152;
    const float* bias = bias_base + br * DM;
    unsigned short* Hout = (br == 0) ? h0 : (br == 1) ? h1 : h2;
#pragma unroll
    for (int it = 0; it < 4; ++it) {
        int q = w * 4 + it;
        gld16(xnm + (size_t)r0 * 128 + q * 512 + lane * 8, &AsX[q * 512]);
    }
#pragma unroll
    for (int it = 0; it < 8; ++it) {
        int q = w * 8 + it;
        gld16(ynm + (size_t)r0 * 256 + q * 512 + lane * 8, &AsY[q * 512]);
    }
    __syncthreads();
    const int lr = w * 16 + l15;
    short8 af[12];
#pragma unroll
    for (int kb = 0; kb < 4; ++kb) {
        int b = kb * 4 + g;
        int bs = (b & 8) | ((b & 7) ^ (lr & 7));
        af[kb] = *(const short8*)&AsX[lr * 128 + bs * 8];
    }
#pragma unroll
    for (int kb = 4; kb < 12; ++kb) {
        int b = (kb - 4) * 4 + g;
        int bs = (b & 24) | ((b & 7) ^ (lr & 7));
        af[kb] = *(const short8*)&AsY[lr * 256 + bs * 8];
    }
    f32x4 acc[8];
#pragma unroll
    for (int c = 0; c < 8; ++c) acc[c] = (f32x4){0.f, 0.f, 0.f, 0.f};
    short8 bfA[8], bfB[8];
#pragma unroll
    for (int c = 0; c < 8; ++c)
        bfA[c] = *(const short8*)&Bc[(size_t)(c * 16 + l15) * 384 + g * 8];
#pragma unroll
    for (int kb = 0; kb < 12; ++kb) {
        if (kb + 1 < 12) {
#pragma unroll
            for (int c = 0; c < 8; ++c) {
                short8 v = *(const short8*)&Bc[(size_t)(c * 16 + l15) * 384 + (kb + 1) * 32 + g * 8];
                if (kb & 1) bfA[c] = v; else bfB[c] = v;
            }
        }
#pragma unroll
        for (int c = 0; c < 8; ++c)
            acc[c] = __builtin_amdgcn_mfma_f32_16x16x32_bf16(af[kb], (kb & 1) ? bfB[c] : bfA[c], acc[c], 0, 0, 0);
    }
#pragma unroll
    for (int c = 0; c < 8; ++c) {
        int o = c * 16 + l15;
        float bv = (o < 120) ? bias[o] : 0.f;
#pragma unroll
        for (int r = 0; r < 4; ++r) {
            int row = r0 + w * 16 + g * 4 + r;
            float v = (o < 120) ? fmaxf(acc[c][r] + bv, 0.f) : 0.f;
            Hout[(size_t)row * 128 + o] = f2bf(v);
        }
    }
}

// ================= attention core: softmax(QK^T/s)V per (b, 2 nodes) =================
#define QP 136   // padded row stride (272B = 17x16B, bank-stride 4)
__global__ __launch_bounds__(192)
void k_attn_qkv(const unsigned short* __restrict__ hq, const unsigned short* __restrict__ hk,
                const unsigned short* __restrict__ hv, unsigned short* __restrict__ onm) {
    __shared__ unsigned short qs[2][SEQ][QP], ks[2][SEQ][QP], vs[2][SEQ][QP], os[2][SEQ][QP];
    const int tid = threadIdx.x;
    const int np = blockIdx.x, b = blockIdx.y;
    for (int u = tid; u < 2 * SEQ * 16; u += 192) {
        int node = u / (SEQ * 16);
        int rem = u - node * SEQ * 16;
        int t = rem >> 4, seg = rem & 15;
        int n = np * 2 + node;
        size_t row = ((size_t)(b * SEQ + t) * N_NODES + n);
        *(uint4*)&qs[node][t][seg * 8] = *(const uint4*)&hq[row * 128 + seg * 8];
        *(uint4*)&ks[node][t][seg * 8] = *(const uint4*)&hk[row * 128 + seg * 8];
        *(uint4*)&vs[node][t][seg * 8] = *(const uint4*)&hv[row * 128 + seg * 8];
    }
    __syncthreads();
    {
        const int node = tid / 96, sub = tid % 96;
        const int h = sub & 7, tq = sub >> 3;
        float qr[15];
#pragma unroll
        for (int d = 0; d < 15; ++d) qr[d] = bf2f(qs[node][tq][h * 15 + d]);
        float sc[SEQ];
        float mx = -1e30f;
#pragma unroll
        for (int tk = 0; tk < SEQ; ++tk) {
            float s = 0.f;
#pragma unroll
            for (int d = 0; d < 15; ++d) s += qr[d] * bf2f(ks[node][tk][h * 15 + d]);
            s *= 0.25819888974716113f;
            sc[tk] = s;
            mx = fmaxf(mx, s);
        }
        float sum = 0.f;
#pragma unroll
        for (int tk = 0; tk < SEQ; ++tk) { sc[tk] = __expf(sc[tk] - mx); sum += sc[tk]; }
        float inv = 1.f / sum;
#pragma unroll
        for (int d = 0; d < 15; ++d) {
            float o = 0.f;
#pragma unroll
            for (int tk = 0; tk < SEQ; ++tk) o += sc[tk] * bf2f(vs[node][tk][h * 15 + d]);
            os[node][tq][h * 15 + d] = f2bf(o * inv);
        }
        if (sub < SEQ * 2) {       // zero pad cols 120..127 (24 tasks: node x t x ... )
            int nd = sub >> 3;     // careful: use separate mapping below
        }
    }
    // zero pad cols 120..127 for all 24 rows
    if (tid < 2 * SEQ) {
        int node = tid / SEQ, t = tid % SEQ;
#pragma unroll
        for (int j = 0; j < 8; ++j) os[node][t][120 + j] = 0;
    }
    __syncthreads();
    for (int u = tid; u < 2 * SEQ * 16; u += 192) {
        int node = u / (SEQ * 16);
        int rem = u - node * SEQ * 16;
        int t = rem >> 4, seg = rem & 15;
        int n = np * 2 + node;
        unsigned int row = (b * SEQ + t) * N_NODES + n;
        int bs = (seg & 8) | ((seg & 7) ^ (row & 7));
        *(uint4*)&onm[(size_t)row * 128 + bs * 8] = *(const uint4*)&os[node][t][seg * 8];
    }
}

// ================= out_w prep: OwT[o=128][c=128] bf16 =================
__global__ __launch_bounds__(256)
void k_prep_ow(const float* __restrict__ out_w, unsigned short* __restrict__ OwT) {
    int idx = blockIdx.x * 256 + threadIdx.x;   // 128*128
    int o = idx >> 7, c = idx & 127;
    float v = (o < 120 && c < 120) ? out_w[(size_t)c * 120 + o] : 0.f;
    OwT[idx] = f2bf(v);
}

// ================= MFMA out-proj + residual + LN1 =================
__global__ __launch_bounds__(256)
void k_outproj(const unsigned short* __restrict__ onm, const unsigned short* __restrict__ OwT,
               const float* __restrict__ outb, const float* __restrict__ x,
               const float* __restrict__ g1, const float* __restrict__ be1,
               float* __restrict__ ln1, unsigned short* __restrict__ ln1bf) {
    __shared__ __attribute__((aligned(16))) unsigned short As[64 * 128];
    const int tid = threadIdx.x, w = tid >> 6, lane = tid & 63;
    const int g = lane >> 4, l15 = lane & 15;
    const int r0 = blockIdx.x * 64;
#pragma unroll
    for (int it = 0; it < 4; ++it) {
        int q = w * 4 + it;
        gld16(onm + (size_t)r0 * 128 + q * 512 + lane * 8, &As[q * 512]);
    }
    __syncthreads();
    const int lr = w * 16 + l15;
    short8 af[4];
#pragma unroll
    for (int kb = 0; kb < 4; ++kb) {
        int b = kb * 4 + g;
        int bs = (b & 8) | ((b & 7) ^ (lr & 7));
        af[kb] = *(const short8*)&As[lr * 128 + bs * 8];
    }
    f32x4 acc[8];
#pragma unroll
    for (int c = 0; c < 8; ++c) acc[c] = (f32x4){0.f, 0.f, 0.f, 0.f};
#pragma unroll
    for (int kb = 0; kb < 4; ++kb) {
#pragma unroll
        for (int c = 0; c < 8; ++c) {
            short8 bf = *(const short8*)&OwT[(size_t)(c * 16 + l15) * 128 + kb * 32 + g * 8];
            acc[c] = __builtin_amdgcn_mfma_f32_16x16x32_bf16(af[kb], bf, acc[c], 0, 0, 0);
        }
    }
    // epilogue: +out_b, +x residual, LN1; write ln1 fp32 + ln1bf bf16
#pragma unroll
    for (int r = 0; r < 4; ++r) {
        int row = w * 16 + g * 4 + r;
        size_t grow = (size_t)(r0 + row);
        float vals[8];
        float s = 0.f, q = 0.f;
#pragma unroll
        for (int c = 0; c < 8; ++c) {
            int col = c * 16 + l15;
            float v = 0.f;
            if (col < DM) v = acc[c][r] + outb[col] + x[grow * DM + col];
            vals[c] = v;
            s += v; q += v * v;
        }
#pragma unroll
        for (int m = 1; m < 16; m <<= 1) {
            s += __shfl_xor(s, m);
            q += __shfl_xor(q, m);
        }
        float mean = s * (1.f / DM);
        float var  = q * (1.f / DM) - mean * mean;
        float rstd = rsqrtf(var + 1e-5f);
#pragma unroll
        for (int c = 0; c < 8; ++c) {
            int col = c * 16 + l15;
            float o = (vals[c] - mean) * rstd * ((col < DM) ? g1[col] : 0.f) + ((col < DM) ? be1[col] : 0.f);
            if (col < DM) ln1[grow * DM + col] = o;
            ln1bf[grow * 128 + col] = (col < DM) ? f2bf(o) : (unsigned short)0;
        }
    }
}

// ================= FFN weight prep =================
__global__ __launch_bounds__(256)
void k_prep_w1(const float* __restrict__ W1, unsigned short* __restrict__ W1T) {
    int idx = blockIdx.x * 256 + threadIdx.x;
    int o = idx >> 7, k = idx & 127;
    int b = k >> 3, ki = k & 7;
    int pos = (((b ^ (o & 7)) << 3) | ki);
    float v = (k < DM) ? W1[(size_t)k * FF + o] : 0.f;
    W1T[(size_t)o * 128 + pos] = f2bf(v);
}
__global__ __launch_bounds__(256)
void k_prep_w2(const float* __restrict__ W2, unsigned short* __restrict__ W2R) {
    int idx = blockIdx.x * 256 + threadIdx.x;
    int c = idx >> 13;
    int o = (idx >> 6) & 127;
    int j = idx & 63;
    int b = j >> 3, ji = j & 7;
    int pos = (((b ^ (o & 7)) << 3) | ji);
    float v = (o < DM) ? W2[(size_t)(c * 64 + j) * DM + o] : 0.f;
    W2R[((size_t)c << 13) + (o << 6) + pos] = f2bf(v);
}

// ================= MFMA FFN: O = LN2( X + relu(X@W1+b1)@W2 + b2 ) =================
#define LDS_XW1A 0
#define LDS_W1B  8192
#define LDS_W2A  16384
#define LDS_W2B  24576
#define LDS_HS   32768
__global__ __launch_bounds__(256, 2)
void k_ffn_mfma(const unsigned short* __restrict__ Xbf,
                const float* __restrict__ ln1,
                const unsigned short* __restrict__ W1T,
                const float* __restrict__ b1,
                const unsigned short* __restrict__ W2R,
                const float* __restrict__ b2,
                const float* __restrict__ g2, const float* __restrict__ be2,
                float* __restrict__ Out) {
    __shared__ unsigned short lds[37376];
    const int tid  = threadIdx.x;
    const int w    = tid >> 6;
    const int lane = tid & 63;
    const int g    = lane >> 4;
    const int l15  = lane & 15;
    const int r0   = blockIdx.x * 64;
    {
        const unsigned short* xsrc = Xbf + (size_t)r0 * 128;
#pragma unroll
        for (int it = 0; it < 4; ++it) {
            int seg = w * 4 + it;
            gld16(xsrc + seg * 512 + lane * 8, &lds[LDS_XW1A + seg * 512]);
        }
#pragma unroll
        for (int it = 0; it < 4; ++it) {
            int seg = w * 4 + it;
            gld16(W1T + seg * 512 + lane * 8, &lds[LDS_W1B + seg * 512]);
        }
#pragma unroll
        for (int it = 0; it < 4; ++it) {
            int seg = w * 4 + it;
            gld16(W2R + seg * 512 + lane * 8, &lds[LDS_W2A + seg * 512]);
        }
    }
    __syncthreads();
    short8 xfrag[4][4];
#pragma unroll
    for (int rt = 0; rt < 4; ++rt)
#pragma unroll
        for (int kk = 0; kk < 4; ++kk)
            xfrag[rt][kk] = *(const short8*)&lds[LDS_XW1A + (rt * 16 + l15) * 128 + kk * 32 + g * 8];

    f32x4 accO[8] = {};
    const int mycolA = w * 16 + l15;
    const int myrowB = w * 16 + l15;

    for (int t = 0; t < 32; ++t) {
        __syncthreads();
        const int p = t & 1;
        if (t + 1 < 32) {
            const unsigned short* w1src = W1T + (size_t)(t + 1) * 8192;
            const unsigned short* w2src = W2R + (size_t)(t + 1) * 8192;
            unsigned short* w1dst = &lds[(p ? LDS_W1B : LDS_XW1A)];
            unsigned short* w2dst = &lds[(p ? LDS_W2A : LDS_W2B)];
#pragma unroll
            for (int it = 0; it < 4; ++it) {
                int seg = w * 4 + it;
                gld16(w1src + seg * 512 + lane * 8, w1dst + seg * 512);
                gld16(w2src + seg * 512 + lane * 8, w2dst + seg * 512);
            }
        }
        {
            const unsigned short* w1p = &lds[p ? LDS_XW1A : LDS_W1B];
            f32x4 accA[4] = {};
#pragma unroll
            for (int kk = 0; kk < 4; ++kk) {
                int b = kk * 4 + g;
                short8 bfrag = *(const short8*)&w1p[mycolA * 128 + ((b ^ (mycolA & 7)) << 3)];
#pragma unroll
                for (int rt = 0; rt < 4; ++rt)
                    accA[rt] = __builtin_amdgcn_mfma_f32_16x16x32_bf16(xfrag[rt][kk], bfrag, accA[rt], 0, 0, 0);
            }
            float b1v = b1[t * 64 + mycolA];
#pragma unroll
            for (int rt = 0; rt < 4; ++rt)
#pragma unroll
                for (int r = 0; r < 4; ++r) {
                    float v = fmaxf(accA[rt][r] + b1v, 0.f);
                    lds[LDS_HS + (rt * 16 + g * 4 + r) * 72 + mycolA] = f2bf(v);
                }
        }
        asm volatile("s_waitcnt lgkmcnt(0)" ::: "memory");
        __builtin_amdgcn_sched_barrier(0);
        __builtin_amdgcn_s_barrier();
        {
            const unsigned short* w2p = &lds[p ? LDS_W2B : LDS_W2A];
#pragma unroll
            for (int kk = 0; kk < 2; ++kk) {
                short8 hfrag = *(const short8*)&lds[LDS_HS + myrowB * 72 + kk * 32 + g * 8];
                int b = kk * 4 + g;
#pragma unroll
                for (int c = 0; c < 8; ++c) {
                    int o = c * 16 + l15;
                    short8 w2frag = *(const short8*)&w2p[(o << 6) + ((b ^ (o & 7)) << 3)];
                    accO[c] = __builtin_amdgcn_mfma_f32_16x16x32_bf16(hfrag, w2frag, accO[c], 0, 0, 0);
                }
            }
        }
    }
#pragma unroll
    for (int r = 0; r < 4; ++r) {
        int row = w * 16 + g * 4 + r;
        size_t grow = (size_t)(r0 + row);
        float vals[8];
        float s = 0.f, q = 0.f;
#pragma unroll
        for (int c = 0; c < 8; ++c) {
            int col = c * 16 + l15;
            float v = 0.f;
            if (col < DM) v = accO[c][r] + b2[col] + ln1[grow * DM + col];
            vals[c] = v;
            s += v; q += v * v;
        }
#pragma unroll
        for (int m = 1; m < 16; m <<= 1) {
            s += __shfl_xor(s, m);
            q += __shfl_xor(q, m);
        }
        float mean = s * (1.f / DM);
        float var  = q * (1.f / DM) - mean * mean;
        float rstd = rsqrtf(var + 1e-5f);
#pragma unroll
        for (int c = 0; c < 8; ++c) {
            int col = c * 16 + l15;
            if (col < DM)
                Out[grow * DM + col] = (vals[c] - mean) * rstd * g2[col] + be2[col];
        }
    }
}

// ================================ launch ================================
extern "C" void kernel_launch(void* const* d_in, const int* in_sizes, int n_in,
                              void* d_out, int out_size, void* d_ws, size_t ws_size,
                              hipStream_t stream) {
    const float* x      = (const float*)d_in[0];
    const float* adj    = (const float*)d_in[1];
    const float* gl_beta= (const float*)d_in[2];
    const float* gl_w1  = (const float*)d_in[3];
    const float* gl_w2  = (const float*)d_in[4];
    const float* gl_cw  = (const float*)d_in[5];
    const float* gl_cb  = (const float*)d_in[6];
    const float* cheb_w = (const float*)d_in[7];
    const float* cheb_b = (const float*)d_in[8];
    const float* out_w  = (const float*)d_in[9];
    const float* out_b  = (const float*)d_in[10];
    const float* ff_w1  = (const float*)d_in[11];
    const float* ff_b1  = (const float*)d_in[12];
    const float* ff_w2  = (const float*)d_in[13];
    const float* ff_b2  = (const float*)d_in[14];
    const float* ln1_g  = (const float*)d_in[15];
    const float* ln1_b  = (const float*)d_in[16];
    const float* ln2_g  = (const float*)d_in[17];
    const float* ln2_b  = (const float*)d_in[18];

    float* ws    = (float*)d_ws;
    float* a_buf = ws + OFF_A;
    float* g_buf = ws + OFF_G;
    float* a2buf = ws + OFF_A2;
    float* rs1   = ws + OFF_RS1;
    float* rs2   = ws + OFF_RS2;
    float* rs3   = ws + OFF_RS3;
    unsigned short* L_bf = (unsigned short*)(ws + OFF_L);
    unsigned short* xT   = (unsigned short*)(ws + OFF_XT);
    unsigned short* xnm  = (unsigned short*)(ws + OFF_XNM);
    unsigned short* y1T  = (unsigned short*)(ws + OFF_Y1T);
    unsigned short* ynm  = (unsigned short*)(ws + OFF_YNM);
    unsigned short* Bc   = (unsigned short*)(ws + OFF_BC);
    unsigned short* hq   = (unsigned short*)(ws + OFF_HQ);
    unsigned short* hk   = (unsigned short*)(ws + OFF_HK);
    unsigned short* hv   = (unsigned short*)(ws + OFF_HV);
    unsigned short* W1T  = (unsigned short*)(ws + OFF_W1T);
    unsigned short* W2R  = (unsigned short*)(ws + OFF_W2R);
    unsigned short* onm  = (unsigned short*)(ws + OFF_ONM);
    float*          ln1  = ws + OFF_LN1;
    unsigned short* ln1bf= (unsigned short*)(ws + OFF_LN1B);
    unsigned short* OwT  = (unsigned short*)(ws + OFF_OWT);

    // graph learning
    k_gl1   <<<dim3(N_NODES, 3), 256, 0, stream>>>(adj, gl_beta, gl_w1, gl_w2, gl_cw, gl_cb, a_buf, rs1);
    k_glnorm<<<dim3(N_NODES, 3), 256, 0, stream>>>(a_buf, rs1, a2buf, rs2, 2);
    k_glnorm<<<dim3(N_NODES, 3), 256, 0, stream>>>(a2buf, rs2, g_buf, rs3, 3);
    k_prep_L<<<dim3(176, 3), 192, 0, stream>>>(g_buf, rs3, L_bf);

    // preps
    k_prep_x <<<BT, 256, 0, stream>>>(x, xT, xnm);
    k_prep_Bc<<<576, 256, 0, stream>>>(cheb_w, Bc);

    // Cheb hops (all branches per dispatch)
    k_lapplyT<<<dim3(BT, 3), 256, 0, stream>>>(xT, 0, L_bf, y1T, ynm, 0);
    k_lapplyT<<<dim3(BT, 3), 256, 0, stream>>>(y1T, Y1T_BR_STRIDE, L_bf, nullptr, ynm, 128);

    // Cheb combine (all branches)
    k_combine_mfma<<<dim3(ROWS / 64, 3), 256, 0, stream>>>(xnm, ynm, Bc, cheb_b, hq, hk, hv);

    // weight preps (ynm region dead)
    k_prep_w1<<<(2048 * 128) / 256, 256, 0, stream>>>(ff_w1, W1T);
    k_prep_w2<<<(32 * 128 * 64) / 256, 256, 0, stream>>>(ff_w2, W2R);
    k_prep_ow<<<64, 256, 0, stream>>>(out_w, OwT);

    // attention core -> o_nm (bf16 swizzled)
    k_attn_qkv<<<dim3(N_NODES / 2, BATCH), 192, 0, stream>>>(hq, hk, hv, onm);

    // out-proj + residual + LN1 (MFMA)
    k_outproj<<<ROWS / 64, 256, 0, stream>>>(onm, OwT, out_b, x, ln1_g, ln1_b, ln1, ln1bf);

    // FFN + residual + LN2 -> output
    k_ffn_mfma<<<ROWS / 64, 256, 0, stream>>>(ln1bf, ln1, W1T, ff_b1, W2R, ff_b2, ln2_g, ln2_b, (float*)d_out);
}

// Round 5
// 457.613 us; speedup vs baseline: 14.3515x; 1.2059x over previous
//
#include <hip/hip_runtime.h>
#include <cstddef>
#include <cstdint>

#define N_NODES 170
#define SEQ 12
#define BATCH 32
#define DM 120
#define BT (BATCH*SEQ)          // 384
#define ROWS (BT*N_NODES)       // 65280
#define FF 2048

typedef short short8 __attribute__((ext_vector_type(8)));
typedef float f32x4 __attribute__((ext_vector_type(4)));

// ---------------- workspace layout (floats) ----------------
static constexpr size_t OFF_A    = 0;          // 86,704
static constexpr size_t OFF_G    = 86704;
static constexpr size_t OFF_A2   = 173408;
static constexpr size_t OFF_L    = 260112;     // L_bf bf16 3*31808 ush
static constexpr size_t OFF_RS1  = 307824;
static constexpr size_t OFF_RS2  = 308336;
static constexpr size_t OFF_RS3  = 308848;
static constexpr size_t OFF_XT   = 309360;                     // 4,325,376 fl (frag-linear 22x128x8 ush per bt)
static constexpr size_t OFF_XNM  = OFF_XT  + 4325376;          // 4,177,920
static constexpr size_t OFF_Y1T  = OFF_XNM + 4177920;          // 3x4,325,376
static constexpr size_t OFF_YNM  = OFF_Y1T + 3*4325376;        // 3x8,355,840
static constexpr size_t OFF_BC   = OFF_YNM + 3*8355840;        // 73,728 -> end 46,930,032 (<47,350,016 proven)
// aliases (regions dead at time of use):
static constexpr size_t OFF_HQ   = OFF_XT;
static constexpr size_t OFF_HK   = OFF_Y1T;
static constexpr size_t OFF_HV   = OFF_Y1T + 4177920;
static constexpr size_t OFF_W1T  = OFF_YNM;
static constexpr size_t OFF_W2R  = OFF_W1T + 131072;
static constexpr size_t OFF_ONM  = OFF_W2R + 131072;
static constexpr size_t OFF_LN1  = OFF_ONM + 4177920;
static constexpr size_t OFF_LN1B = OFF_LN1 + 7833600;
static constexpr size_t OFF_OWT  = OFF_LN1B + 4177920;

static constexpr size_t Y1T_BR_STRIDE = 8650752;   // ushorts per branch
static constexpr size_t YNM_BR_STRIDE = 16711680;  // ushorts per branch

__device__ __forceinline__ unsigned short f2bf(float f) {
    unsigned int u = __float_as_uint(f);
    unsigned int r = (u + 0x7fffu + ((u >> 16) & 1u)) >> 16;
    return (unsigned short)r;
}
__device__ __forceinline__ float bf2f(unsigned short h) {
    return __uint_as_float(((unsigned int)h) << 16);
}
__device__ __forceinline__ void gld16(const void* g, void* l) {
    __builtin_amdgcn_global_load_lds(
        (const __attribute__((address_space(1))) void*)g,
        (__attribute__((address_space(3))) void*)l, 16, 0, 0);
}
__device__ __forceinline__ uint4 pack8(const unsigned short v[8]) {
    uint4 q;
    q.x = (unsigned)v[0] | ((unsigned)v[1] << 16);
    q.y = (unsigned)v[2] | ((unsigned)v[3] << 16);
    q.z = (unsigned)v[4] | ((unsigned)v[5] << 16);
    q.w = (unsigned)v[6] | ((unsigned)v[7] << 16);
    return q;
}

// ================= graph-learn stage 1 =================
__global__ __launch_bounds__(256)
void k_gl1(const float* __restrict__ adj, const float* __restrict__ beta,
           const float* __restrict__ w1, const float* __restrict__ w2,
           const float* __restrict__ cw, const float* __restrict__ cb,
           float* __restrict__ a_out, float* __restrict__ rs_out) {
    int i  = blockIdx.x;
    int br = blockIdx.y;
    __shared__ float w1r[DM], w2r[DM];
    __shared__ float red[256];
    int tid = threadIdx.x;
    const float* w1b = w1 + (size_t)br * N_NODES * DM;
    const float* w2b = w2 + (size_t)br * N_NODES * DM;
    if (tid < DM) {
        w1r[tid] = w1b[(size_t)i * DM + tid];
        w2r[tid] = w2b[(size_t)i * DM + tid];
    }
    __syncthreads();
    float aval = 0.f;
    if (tid < N_NODES) {
        int j = tid;
        const float4* w1j = (const float4*)(w1b + (size_t)j * DM);
        const float4* w2j = (const float4*)(w2b + (size_t)j * DM);
        float s1 = 0.f, s2 = 0.f;
#pragma unroll 6
        for (int cc = 0; cc < DM / 4; ++cc) {
            float4 u = w2j[cc];
            float4 v = w1j[cc];
            s1 += w1r[cc*4+0]*u.x + w1r[cc*4+1]*u.y + w1r[cc*4+2]*u.z + w1r[cc*4+3]*u.w;
            s2 += w2r[cc*4+0]*v.x + w2r[cc*4+1]*v.y + w2r[cc*4+2]*v.z + w2r[cc*4+3]*v.w;
        }
        float nv = s1 - s2 + (j == i ? beta[br * N_NODES + i] : 0.f);
        nv = fmaxf(nv, 0.f);
        float adjv = adj[(size_t)i * N_NODES + j];
        float z = cw[br*2+0] * nv + cw[br*2+1] * adjv + cb[br];
        float gate = 1.f / (1.f + __expf(-z));
        aval = gate * nv + (1.f - gate) * adjv;
        a_out[((size_t)br * N_NODES + i) * N_NODES + j] = aval;
    }
    red[tid] = aval;
    __syncthreads();
    for (int s = 128; s > 0; s >>= 1) {
        if (tid < s) red[tid] += red[tid + s];
        __syncthreads();
    }
    if (tid == 0) rs_out[br * N_NODES + i] = red[0];
}

// ================= graph-learn normalize passes (modes 2,3) =================
__global__ __launch_bounds__(256)
void k_glnorm(const float* __restrict__ in, const float* __restrict__ rs,
              float* __restrict__ out, float* __restrict__ rs_out, int mode) {
    int i  = blockIdx.x;
    int br = blockIdx.y;
    __shared__ float red[256];
    int tid = threadIdx.x;
    float di = rsqrtf(rs[br * N_NODES + i]);
    float contrib = 0.f;
    if (tid < N_NODES) {
        float dj = rsqrtf(rs[br * N_NODES + tid]);
        float v = di * in[((size_t)br * N_NODES + i) * N_NODES + tid] * dj;
        float o;
        if (mode == 2) { o = fmaxf(v - 0.5f / 170.f, 0.f); contrib = o; }
        else           { o = v; contrib = v; }
        out[((size_t)br * N_NODES + i) * N_NODES + tid] = o;
    }
    red[tid] = contrib;
    __syncthreads();
    for (int s = 128; s > 0; s >>= 1) {
        if (tid < s) red[tid] += red[tid + s];
        __syncthreads();
    }
    if (tid == 0) rs_out[br * N_NODES + i] = red[0];
}

// ================= L prep: L_bf[br][176][180] bf16, zero-padded =================
__global__ __launch_bounds__(192)
void k_prep_L(const float* __restrict__ g_buf, const float* __restrict__ rs3,
              unsigned short* __restrict__ Lbf) {
    int i  = blockIdx.x;   // 0..175
    int br = blockIdx.y;
    int j  = threadIdx.x;
    if (j >= 180) return;
    float v = 0.f;
    if (i < N_NODES && j < N_NODES) {
        float di = rsqrtf(rs3[br * N_NODES + i]);
        float dj = rsqrtf(rs3[br * N_NODES + j]);
        float gg = g_buf[((size_t)br * N_NODES + i) * N_NODES + j];
        v = (i == j ? 1.f : 0.f) - di * gg * dj;
    }
    Lbf[(size_t)br * 31808 + i * 180 + j] = f2bf(v);
}

// ================= x prep: xTF (FRAG-LINEAR channel-major) + x_nm (node-major swizzled) =========
// xTF[bt][f][c][j]: f = node-k-block (m>>3, 0..21), c = channel 0..127, j = m&7
__global__ __launch_bounds__(256)
void k_prep_x(const float* __restrict__ x, unsigned short* __restrict__ xTF,
              unsigned short* __restrict__ xnm) {
    __shared__ unsigned short LX[170 * 121 + 8];
    int bt = blockIdx.x, tid = threadIdx.x;
    const float* xb = x + (size_t)bt * N_NODES * DM;
    for (int u = tid; u < 170 * 30; u += 256) {
        int nn = u / 30, cq = u - nn * 30;
        float4 v = *(const float4*)&xb[nn * 120 + cq * 4];
        LX[nn * 121 + cq * 4 + 0] = f2bf(v.x);
        LX[nn * 121 + cq * 4 + 1] = f2bf(v.y);
        LX[nn * 121 + cq * 4 + 2] = f2bf(v.z);
        LX[nn * 121 + cq * 4 + 3] = f2bf(v.w);
    }
    __syncthreads();
    // frag-linear: 8 consecutive nodes (m-block mb) per (mb, c)
    for (int u = tid; u < 128 * 22; u += 256) {
        int c = u / 22, mb = u - c * 22;
        unsigned short vals[8];
#pragma unroll
        for (int i2 = 0; i2 < 8; ++i2) {
            int m = mb * 8 + i2;
            vals[i2] = (c < 120 && m < 170) ? LX[m * 121 + c] : (unsigned short)0;
        }
        *(uint4*)&xTF[(size_t)bt * 22528 + ((size_t)mb * 128 + c) * 8] = pack8(vals);
    }
    for (int u = tid; u < 170 * 16; u += 256) {
        int nn = u >> 4, b = u & 15;
        unsigned int row = bt * 170 + nn;
        unsigned short vals[8];
#pragma unroll
        for (int i2 = 0; i2 < 8; ++i2) {
            int c = b * 8 + i2;
            vals[i2] = (c < 120) ? LX[nn * 121 + c] : (unsigned short)0;
        }
        int bs = (b & 8) | ((b & 7) ^ (row & 7));
        *(uint4*)&xnm[(size_t)row * 128 + bs * 8] = pack8(vals);
    }
}

// ================= Cheb weight prep: FRAG-LINEAR BcF[br][f=c>>3][o][j=c&7] =================
__global__ __launch_bounds__(256)
void k_prep_Bc(const float* __restrict__ cheb_w, unsigned short* __restrict__ Bc) {
    int idx = blockIdx.x * 256 + threadIdx.x;   // 3*128*384
    int br  = idx / 49152;
    int rem = idx - br * 49152;
    int o   = rem / 384;
    int c   = rem - o * 384;
    float v = 0.f;
    if (o < 120) {
        int part = c >> 7, cc = c & 127;
        if (cc < 120) {
            const float* Wb = cheb_w + (size_t)br * 3 * 14400;
            if (part == 0)      v = Wb[cc * 120 + o] - Wb[2 * 14400 + cc * 120 + o];
            else if (part == 1) v = Wb[14400 + cc * 120 + o];
            else                v = 2.f * Wb[2 * 14400 + cc * 120 + o];
        }
    }
    Bc[(size_t)br * 49152 + (((size_t)(c >> 3) * 128 + o) << 3) + (c & 7)] = f2bf(v);
}

// ================= T-form L-apply (frag-linear A) =================
__global__ __launch_bounds__(256)
void k_lapplyT(const unsigned short* __restrict__ Asrc_base, size_t asrc_br_stride,
               const unsigned short* __restrict__ Lg_base,
               unsigned short* __restrict__ yT_base,
               unsigned short* __restrict__ ynm_base, int coloff) {
    __shared__ __attribute__((aligned(16))) unsigned short Llds[31744];
    const int tid = threadIdx.x, w = tid >> 6, lane = tid & 63;
    const int g = lane >> 4, l15 = lane & 15;
    const int bt = blockIdx.x, br = blockIdx.y;
    const unsigned short* Asrc = Asrc_base + (size_t)br * asrc_br_stride + (size_t)bt * 22528;
    const unsigned short* Lg   = Lg_base + (size_t)br * 31808;
    unsigned short* ynm = ynm_base + (size_t)br * YNM_BR_STRIDE;
    unsigned short* yT  = yT_base ? yT_base + (size_t)br * Y1T_BR_STRIDE + (size_t)bt * 22528 : nullptr;
    const char* Lgb = (const char*)Lg;
    char* Lldsb = (char*)Llds;
#pragma unroll
    for (int it = 0; it < 16; ++it) {
        int q = it * 4 + w;
        if (q * 1024 < 63360)
            gld16(Lgb + q * 1024 + lane * 16, Lldsb + q * 1024);
    }
    // A-frags, frag-linear: f = kb*4+g (<22), addr = (f*128 + c)*8
    short8 af[2][6];
#pragma unroll
    for (int ct2 = 0; ct2 < 2; ++ct2) {
        int c = (w * 2 + ct2) * 16 + l15;
#pragma unroll
        for (int kb = 0; kb < 6; ++kb) {
            if (kb < 5) af[ct2][kb] = *(const short8*)&Asrc[(((size_t)(kb * 4 + g)) * 128 + c) * 8];
            else {
                short8 z = {};
                af[ct2][kb] = (g < 2) ? *(const short8*)&Asrc[(((size_t)(20 + g)) * 128 + c) * 8] : z;
            }
        }
    }
    __syncthreads();
    f32x4 acc[2][11];
#pragma unroll
    for (int a = 0; a < 2; ++a)
#pragma unroll
        for (int b = 0; b < 11; ++b) acc[a][b] = (f32x4){0.f, 0.f, 0.f, 0.f};
#pragma unroll
    for (int kb = 0; kb < 6; ++kb) {
#pragma unroll
        for (int nt = 0; nt < 11; ++nt) {
            short8 bf;
            int rb = (nt * 16 + l15) * 180;
            if (kb < 5) bf = *(const short8*)&Llds[rb + kb * 32 + g * 8];
            else {
                short8 z = {};
                bf = (g < 2) ? *(const short8*)&Llds[rb + 160 + g * 8] : z;
            }
            acc[0][nt] = __builtin_amdgcn_mfma_f32_16x16x32_bf16(af[0][kb], bf, acc[0][nt], 0, 0, 0);
            acc[1][nt] = __builtin_amdgcn_mfma_f32_16x16x32_bf16(af[1][kb], bf, acc[1][nt], 0, 0, 0);
        }
    }
#pragma unroll
    for (int nt = 0; nt < 11; ++nt) {
        int nn = nt * 16 + l15;
#pragma unroll
        for (int ct2 = 0; ct2 < 2; ++ct2) {
            int base_c = (w * 2 + ct2) * 16 + g * 4;
            if (yT) {
                // frag-linear y1T write: f = nn>>3, j = nn&7
                int f = nn >> 3, j = nn & 7;
#pragma unroll
                for (int r = 0; r < 4; ++r) {
                    int c = base_c + r;
                    float v = (c < 120 && nn < 170) ? acc[ct2][nt][r] : 0.f;
                    yT[(((size_t)f * 128 + c) << 3) + j] = f2bf(v);
                }
            }
            if (nn < 170) {
                unsigned int row = bt * 170 + nn;
                unsigned short u[4];
#pragma unroll
                for (int r = 0; r < 4; ++r)
                    u[r] = (base_c + r < 120) ? f2bf(acc[ct2][nt][r]) : (unsigned short)0;
                int bc  = coloff + base_c;
                int blk = bc >> 3;
                int bsw = (blk & 24) | ((blk & 7) ^ (row & 7));
                uint2 pk;
                pk.x = (unsigned)u[0] | ((unsigned)u[1] << 16);
                pk.y = (unsigned)u[2] | ((unsigned)u[3] << 16);
                *(uint2*)&ynm[(size_t)row * 256 + bsw * 8 + (bc & 7)] = pk;
            }
        }
    }
}

// ================= MFMA Cheb combine (frag-linear B) =================
__global__ __launch_bounds__(256)
void k_combine_mfma(const unsigned short* __restrict__ xnm,
                    const unsigned short* __restrict__ ynm_base,
                    const unsigned short* __restrict__ Bc_base,
                    const float* __restrict__ bias_base,
                    unsigned short* __restrict__ h0,
                    unsigned short* __restrict__ h1,
                    unsigned short* __restrict__ h2) {
    __shared__ __attribute__((aligned(16))) unsigned short AsX[64 * 128];
    __shared__ __attribute__((aligned(16))) unsigned short AsY[64 * 256];
    const int tid = threadIdx.x, w = tid >> 6, lane = tid & 63;
    const int g = lane >> 4, l15 = lane & 15;
    const int r0 = blockIdx.x * 64;
    const int br = blockIdx.y;
    const unsigned short* ynm = ynm_base + (size_t)br * YNM_BR_STRIDE;
    const unsigned short* Bc  = Bc_base + (size_t)br * 49152;
    const float* bias = bias_base + br * DM;
    unsigned short* Hout = (br == 0) ? h0 : (br == 1) ? h1 : h2;
#pragma unroll
    for (int it = 0; it < 4; ++it) {
        int q = w * 4 + it;
        gld16(xnm + (size_t)r0 * 128 + q * 512 + lane * 8, &AsX[q * 512]);
    }
#pragma unroll
    for (int it = 0; it < 8; ++it) {
        int q = w * 8 + it;
        gld16(ynm + (size_t)r0 * 256 + q * 512 + lane * 8, &AsY[q * 512]);
    }
    __syncthreads();
    const int lr = w * 16 + l15;
    short8 af[12];
#pragma unroll
    for (int kb = 0; kb < 4; ++kb) {
        int b = kb * 4 + g;
        int bs = (b & 8) | ((b & 7) ^ (lr & 7));
        af[kb] = *(const short8*)&AsX[lr * 128 + bs * 8];
    }
#pragma unroll
    for (int kb = 4; kb < 12; ++kb) {
        int b = (kb - 4) * 4 + g;
        int bs = (b & 24) | ((b & 7) ^ (lr & 7));
        af[kb] = *(const short8*)&AsY[lr * 256 + bs * 8];
    }
    f32x4 acc[8];
#pragma unroll
    for (int c = 0; c < 8; ++c) acc[c] = (f32x4){0.f, 0.f, 0.f, 0.f};
    // frag-linear B: f = kb*4+g (0..47), addr = (f*128 + o)*8
    short8 bfA[8], bfB[8];
#pragma unroll
    for (int c = 0; c < 8; ++c)
        bfA[c] = *(const short8*)&Bc[(((size_t)g) * 128 + c * 16 + l15) * 8];
#pragma unroll
    for (int kb = 0; kb < 12; ++kb) {
        if (kb + 1 < 12) {
#pragma unroll
            for (int c = 0; c < 8; ++c) {
                short8 v = *(const short8*)&Bc[(((size_t)((kb + 1) * 4 + g)) * 128 + c * 16 + l15) * 8];
                if (kb & 1) bfA[c] = v; else bfB[c] = v;
            }
        }
#pragma unroll
        for (int c = 0; c < 8; ++c)
            acc[c] = __builtin_amdgcn_mfma_f32_16x16x32_bf16(af[kb], (kb & 1) ? bfB[c] : bfA[c], acc[c], 0, 0, 0);
    }
#pragma unroll
    for (int c = 0; c < 8; ++c) {
        int o = c * 16 + l15;
        float bv = (o < 120) ? bias[o] : 0.f;
#pragma unroll
        for (int r = 0; r < 4; ++r) {
            int row = r0 + w * 16 + g * 4 + r;
            float v = (o < 120) ? fmaxf(acc[c][r] + bv, 0.f) : 0.f;
            Hout[(size_t)row * 128 + o] = f2bf(v);
        }
    }
}

// ================= attention core: softmax(QK^T/s)V per (b, 2 nodes) =================
#define QP 136
__global__ __launch_bounds__(192)
void k_attn_qkv(const unsigned short* __restrict__ hq, const unsigned short* __restrict__ hk,
                const unsigned short* __restrict__ hv, unsigned short* __restrict__ onm) {
    __shared__ unsigned short qs[2][SEQ][QP], ks[2][SEQ][QP], vs[2][SEQ][QP], os[2][SEQ][QP];
    const int tid = threadIdx.x;
    const int np = blockIdx.x, b = blockIdx.y;
    for (int u = tid; u < 2 * SEQ * 16; u += 192) {
        int node = u / (SEQ * 16);
        int rem = u - node * SEQ * 16;
        int t = rem >> 4, seg = rem & 15;
        int n = np * 2 + node;
        size_t row = ((size_t)(b * SEQ + t) * N_NODES + n);
        *(uint4*)&qs[node][t][seg * 8] = *(const uint4*)&hq[row * 128 + seg * 8];
        *(uint4*)&ks[node][t][seg * 8] = *(const uint4*)&hk[row * 128 + seg * 8];
        *(uint4*)&vs[node][t][seg * 8] = *(const uint4*)&hv[row * 128 + seg * 8];
    }
    __syncthreads();
    {
        const int node = tid / 96, sub = tid % 96;
        const int h = sub & 7, tq = sub >> 3;
        float qr[15];
#pragma unroll
        for (int d = 0; d < 15; ++d) qr[d] = bf2f(qs[node][tq][h * 15 + d]);
        float sc[SEQ];
        float mx = -1e30f;
#pragma unroll
        for (int tk = 0; tk < SEQ; ++tk) {
            float s = 0.f;
#pragma unroll
            for (int d = 0; d < 15; ++d) s += qr[d] * bf2f(ks[node][tk][h * 15 + d]);
            s *= 0.25819888974716113f;
            sc[tk] = s;
            mx = fmaxf(mx, s);
        }
        float sum = 0.f;
#pragma unroll
        for (int tk = 0; tk < SEQ; ++tk) { sc[tk] = __expf(sc[tk] - mx); sum += sc[tk]; }
        float inv = 1.f / sum;
#pragma unroll
        for (int d = 0; d < 15; ++d) {
            float o = 0.f;
#pragma unroll
            for (int tk = 0; tk < SEQ; ++tk) o += sc[tk] * bf2f(vs[node][tk][h * 15 + d]);
            os[node][tq][h * 15 + d] = f2bf(o * inv);
        }
    }
    if (tid < 2 * SEQ) {
        int node = tid / SEQ, t = tid % SEQ;
#pragma unroll
        for (int j = 0; j < 8; ++j) os[node][t][120 + j] = 0;
    }
    __syncthreads();
    for (int u = tid; u < 2 * SEQ * 16; u += 192) {
        int node = u / (SEQ * 16);
        int rem = u - node * SEQ * 16;
        int t = rem >> 4, seg = rem & 15;
        int n = np * 2 + node;
        unsigned int row = (b * SEQ + t) * N_NODES + n;
        int bs = (seg & 8) | ((seg & 7) ^ (row & 7));
        *(uint4*)&onm[(size_t)row * 128 + bs * 8] = *(const uint4*)&os[node][t][seg * 8];
    }
}

// ================= out_w prep: FRAG-LINEAR OwF[f=c>>3][o][j=c&7] =================
__global__ __launch_bounds__(256)
void k_prep_ow(const float* __restrict__ out_w, unsigned short* __restrict__ OwT) {
    int idx = blockIdx.x * 256 + threadIdx.x;   // 128*128
    int o = idx >> 7, c = idx & 127;
    float v = (o < 120 && c < 120) ? out_w[(size_t)c * 120 + o] : 0.f;
    OwT[(((size_t)(c >> 3) * 128 + o) << 3) + (c & 7)] = f2bf(v);
}

// ================= MFMA out-proj + residual + LN1 (frag-linear B) =================
__global__ __launch_bounds__(256)
void k_outproj(const unsigned short* __restrict__ onm, const unsigned short* __restrict__ OwT,
               const float* __restrict__ outb, const float* __restrict__ x,
               const float* __restrict__ g1, const float* __restrict__ be1,
               float* __restrict__ ln1, unsigned short* __restrict__ ln1bf) {
    __shared__ __attribute__((aligned(16))) unsigned short As[64 * 128];
    const int tid = threadIdx.x, w = tid >> 6, lane = tid & 63;
    const int g = lane >> 4, l15 = lane & 15;
    const int r0 = blockIdx.x * 64;
#pragma unroll
    for (int it = 0; it < 4; ++it) {
        int q = w * 4 + it;
        gld16(onm + (size_t)r0 * 128 + q * 512 + lane * 8, &As[q * 512]);
    }
    __syncthreads();
    const int lr = w * 16 + l15;
    short8 af[4];
#pragma unroll
    for (int kb = 0; kb < 4; ++kb) {
        int b = kb * 4 + g;
        int bs = (b & 8) | ((b & 7) ^ (lr & 7));
        af[kb] = *(const short8*)&As[lr * 128 + bs * 8];
    }
    f32x4 acc[8];
#pragma unroll
    for (int c = 0; c < 8; ++c) acc[c] = (f32x4){0.f, 0.f, 0.f, 0.f};
#pragma unroll
    for (int kb = 0; kb < 4; ++kb) {
#pragma unroll
        for (int c = 0; c < 8; ++c) {
            short8 bf = *(const short8*)&OwT[(((size_t)(kb * 4 + g)) * 128 + c * 16 + l15) * 8];
            acc[c] = __builtin_amdgcn_mfma_f32_16x16x32_bf16(af[kb], bf, acc[c], 0, 0, 0);
        }
    }
#pragma unroll
    for (int r = 0; r < 4; ++r) {
        int row = w * 16 + g * 4 + r;
        size_t grow = (size_t)(r0 + row);
        float vals[8];
        float s = 0.f, q = 0.f;
#pragma unroll
        for (int c = 0; c < 8; ++c) {
            int col = c * 16 + l15;
            float v = 0.f;
            if (col < DM) v = acc[c][r] + outb[col] + x[grow * DM + col];
            vals[c] = v;
            s += v; q += v * v;
        }
#pragma unroll
        for (int m = 1; m < 16; m <<= 1) {
            s += __shfl_xor(s, m);
            q += __shfl_xor(q, m);
        }
        float mean = s * (1.f / DM);
        float var  = q * (1.f / DM) - mean * mean;
        float rstd = rsqrtf(var + 1e-5f);
#pragma unroll
        for (int c = 0; c < 8; ++c) {
            int col = c * 16 + l15;
            float o = (vals[c] - mean) * rstd * ((col < DM) ? g1[col] : 0.f) + ((col < DM) ? be1[col] : 0.f);
            if (col < DM) ln1[grow * DM + col] = o;
            ln1bf[grow * 128 + col] = (col < DM) ? f2bf(o) : (unsigned short)0;
        }
    }
}

// ================= FFN weight prep =================
__global__ __launch_bounds__(256)
void k_prep_w1(const float* __restrict__ W1, unsigned short* __restrict__ W1T) {
    int idx = blockIdx.x * 256 + threadIdx.x;
    int o = idx >> 7, k = idx & 127;
    int b = k >> 3, ki = k & 7;
    int pos = (((b ^ (o & 7)) << 3) | ki);
    float v = (k < DM) ? W1[(size_t)k * FF + o] : 0.f;
    W1T[(size_t)o * 128 + pos] = f2bf(v);
}
__global__ __launch_bounds__(256)
void k_prep_w2(const float* __restrict__ W2, unsigned short* __restrict__ W2R) {
    int idx = blockIdx.x * 256 + threadIdx.x;
    int c = idx >> 13;
    int o = (idx >> 6) & 127;
    int j = idx & 63;
    int b = j >> 3, ji = j & 7;
    int pos = (((b ^ (o & 7)) << 3) | ji);
    float v = (o < DM) ? W2[(size_t)(c * 64 + j) * DM + o] : 0.f;
    W2R[((size_t)c << 13) + (o << 6) + pos] = f2bf(v);
}

// ================= MFMA FFN: O = LN2( X + relu(X@W1+b1)@W2 + b2 ) =================
#define LDS_XW1A 0
#define LDS_W1B  8192
#define LDS_W2A  16384
#define LDS_W2B  24576
#define LDS_HS   32768
__global__ __launch_bounds__(256, 2)
void k_ffn_mfma(const unsigned short* __restrict__ Xbf,
                const float* __restrict__ ln1,
                const unsigned short* __restrict__ W1T,
                const float* __restrict__ b1,
                const unsigned short* __restrict__ W2R,
                const float* __restrict__ b2,
                const float* __restrict__ g2, const float* __restrict__ be2,
                float* __restrict__ Out) {
    __shared__ unsigned short lds[37376];
    const int tid  = threadIdx.x;
    const int w    = tid >> 6;
    const int lane = tid & 63;
    const int g    = lane >> 4;
    const int l15  = lane & 15;
    const int r0   = blockIdx.x * 64;
    {
        const unsigned short* xsrc = Xbf + (size_t)r0 * 128;
#pragma unroll
        for (int it = 0; it < 4; ++it) {
            int seg = w * 4 + it;
            gld16(xsrc + seg * 512 + lane * 8, &lds[LDS_XW1A + seg * 512]);
        }
#pragma unroll
        for (int it = 0; it < 4; ++it) {
            int seg = w * 4 + it;
            gld16(W1T + seg * 512 + lane * 8, &lds[LDS_W1B + seg * 512]);
        }
#pragma unroll
        for (int it = 0; it < 4; ++it) {
            int seg = w * 4 + it;
            gld16(W2R + seg * 512 + lane * 8, &lds[LDS_W2A + seg * 512]);
        }
    }
    __syncthreads();
    short8 xfrag[4][4];
#pragma unroll
    for (int rt = 0; rt < 4; ++rt)
#pragma unroll
        for (int kk = 0; kk < 4; ++kk)
            xfrag[rt][kk] = *(const short8*)&lds[LDS_XW1A + (rt * 16 + l15) * 128 + kk * 32 + g * 8];

    f32x4 accO[8] = {};
    const int mycolA = w * 16 + l15;
    const int myrowB = w * 16 + l15;

    for (int t = 0; t < 32; ++t) {
        __syncthreads();
        const int p = t & 1;
        if (t + 1 < 32) {
            const unsigned short* w1src = W1T + (size_t)(t + 1) * 8192;
            const unsigned short* w2src = W2R + (size_t)(t + 1) * 8192;
            unsigned short* w1dst = &lds[(p ? LDS_W1B : LDS_XW1A)];
            unsigned short* w2dst = &lds[(p ? LDS_W2A : LDS_W2B)];
#pragma unroll
            for (int it = 0; it < 4; ++it) {
                int seg = w * 4 + it;
                gld16(w1src + seg * 512 + lane * 8, w1dst + seg * 512);
                gld16(w2src + seg * 512 + lane * 8, w2dst + seg * 512);
            }
        }
        {
            const unsigned short* w1p = &lds[p ? LDS_XW1A : LDS_W1B];
            f32x4 accA[4] = {};
#pragma unroll
            for (int kk = 0; kk < 4; ++kk) {
                int b = kk * 4 + g;
                short8 bfrag = *(const short8*)&w1p[mycolA * 128 + ((b ^ (mycolA & 7)) << 3)];
#pragma unroll
                for (int rt = 0; rt < 4; ++rt)
                    accA[rt] = __builtin_amdgcn_mfma_f32_16x16x32_bf16(xfrag[rt][kk], bfrag, accA[rt], 0, 0, 0);
            }
            float b1v = b1[t * 64 + mycolA];
#pragma unroll
            for (int rt = 0; rt < 4; ++rt)
#pragma unroll
                for (int r = 0; r < 4; ++r) {
                    float v = fmaxf(accA[rt][r] + b1v, 0.f);
                    lds[LDS_HS + (rt * 16 + g * 4 + r) * 72 + mycolA] = f2bf(v);
                }
        }
        asm volatile("s_waitcnt lgkmcnt(0)" ::: "memory");
        __builtin_amdgcn_sched_barrier(0);
        __builtin_amdgcn_s_barrier();
        {
            const unsigned short* w2p = &lds[p ? LDS_W2B : LDS_W2A];
#pragma unroll
            for (int kk = 0; kk < 2; ++kk) {
                short8 hfrag = *(const short8*)&lds[LDS_HS + myrowB * 72 + kk * 32 + g * 8];
                int b = kk * 4 + g;
#pragma unroll
                for (int c = 0; c < 8; ++c) {
                    int o = c * 16 + l15;
                    short8 w2frag = *(const short8*)&w2p[(o << 6) + ((b ^ (o & 7)) << 3)];
                    accO[c] = __builtin_amdgcn_mfma_f32_16x16x32_bf16(hfrag, w2frag, accO[c], 0, 0, 0);
                }
            }
        }
    }
#pragma unroll
    for (int r = 0; r < 4; ++r) {
        int row = w * 16 + g * 4 + r;
        size_t grow = (size_t)(r0 + row);
        float vals[8];
        float s = 0.f, q = 0.f;
#pragma unroll
        for (int c = 0; c < 8; ++c) {
            int col = c * 16 + l15;
            float v = 0.f;
            if (col < DM) v = accO[c][r] + b2[col] + ln1[grow * DM + col];
            vals[c] = v;
            s += v; q += v * v;
        }
#pragma unroll
        for (int m = 1; m < 16; m <<= 1) {
            s += __shfl_xor(s, m);
            q += __shfl_xor(q, m);
        }
        float mean = s * (1.f / DM);
        float var  = q * (1.f / DM) - mean * mean;
        float rstd = rsqrtf(var + 1e-5f);
#pragma unroll
        for (int c = 0; c < 8; ++c) {
            int col = c * 16 + l15;
            if (col < DM)
                Out[grow * DM + col] = (vals[c] - mean) * rstd * g2[col] + be2[col];
        }
    }
}

// ================================ launch ================================
extern "C" void kernel_launch(void* const* d_in, const int* in_sizes, int n_in,
                              void* d_out, int out_size, void* d_ws, size_t ws_size,
                              hipStream_t stream) {
    const float* x      = (const float*)d_in[0];
    const float* adj    = (const float*)d_in[1];
    const float* gl_beta= (const float*)d_in[2];
    const float* gl_w1  = (const float*)d_in[3];
    const float* gl_w2  = (const float*)d_in[4];
    const float* gl_cw  = (const float*)d_in[5];
    const float* gl_cb  = (const float*)d_in[6];
    const float* cheb_w = (const float*)d_in[7];
    const float* cheb_b = (const float*)d_in[8];
    const float* out_w  = (const float*)d_in[9];
    const float* out_b  = (const float*)d_in[10];
    const float* ff_w1  = (const float*)d_in[11];
    const float* ff_b1  = (const float*)d_in[12];
    const float* ff_w2  = (const float*)d_in[13];
    const float* ff_b2  = (const float*)d_in[14];
    const float* ln1_g  = (const float*)d_in[15];
    const float* ln1_b  = (const float*)d_in[16];
    const float* ln2_g  = (const float*)d_in[17];
    const float* ln2_b  = (const float*)d_in[18];

    float* ws    = (float*)d_ws;
    float* a_buf = ws + OFF_A;
    float* g_buf = ws + OFF_G;
    float* a2buf = ws + OFF_A2;
    float* rs1   = ws + OFF_RS1;
    float* rs2   = ws + OFF_RS2;
    float* rs3   = ws + OFF_RS3;
    unsigned short* L_bf = (unsigned short*)(ws + OFF_L);
    unsigned short* xT   = (unsigned short*)(ws + OFF_XT);
    unsigned short* xnm  = (unsigned short*)(ws + OFF_XNM);
    unsigned short* y1T  = (unsigned short*)(ws + OFF_Y1T);
    unsigned short* ynm  = (unsigned short*)(ws + OFF_YNM);
    unsigned short* Bc   = (unsigned short*)(ws + OFF_BC);
    unsigned short* hq   = (unsigned short*)(ws + OFF_HQ);
    unsigned short* hk   = (unsigned short*)(ws + OFF_HK);
    unsigned short* hv   = (unsigned short*)(ws + OFF_HV);
    unsigned short* W1T  = (unsigned short*)(ws + OFF_W1T);
    unsigned short* W2R  = (unsigned short*)(ws + OFF_W2R);
    unsigned short* onm  = (unsigned short*)(ws + OFF_ONM);
    float*          ln1  = ws + OFF_LN1;
    unsigned short* ln1bf= (unsigned short*)(ws + OFF_LN1B);
    unsigned short* OwT  = (unsigned short*)(ws + OFF_OWT);

    // graph learning
    k_gl1   <<<dim3(N_NODES, 3), 256, 0, stream>>>(adj, gl_beta, gl_w1, gl_w2, gl_cw, gl_cb, a_buf, rs1);
    k_glnorm<<<dim3(N_NODES, 3), 256, 0, stream>>>(a_buf, rs1, a2buf, rs2, 2);
    k_glnorm<<<dim3(N_NODES, 3), 256, 0, stream>>>(a2buf, rs2, g_buf, rs3, 3);
    k_prep_L<<<dim3(176, 3), 192, 0, stream>>>(g_buf, rs3, L_bf);

    // preps
    k_prep_x <<<BT, 256, 0, stream>>>(x, xT, xnm);
    k_prep_Bc<<<576, 256, 0, stream>>>(cheb_w, Bc);

    // Cheb hops (all branches per dispatch)
    k_lapplyT<<<dim3(BT, 3), 256, 0, stream>>>(xT, 0, L_bf, y1T, ynm, 0);
    k_lapplyT<<<dim3(BT, 3), 256, 0, stream>>>(y1T, Y1T_BR_STRIDE, L_bf, nullptr, ynm, 128);

    // Cheb combine (all branches)
    k_combine_mfma<<<dim3(ROWS / 64, 3), 256, 0, stream>>>(xnm, ynm, Bc, cheb_b, hq, hk, hv);

    // weight preps (ynm region dead)
    k_prep_w1<<<(2048 * 128) / 256, 256, 0, stream>>>(ff_w1, W1T);
    k_prep_w2<<<(32 * 128 * 64) / 256, 256, 0, stream>>>(ff_w2, W2R);
    k_prep_ow<<<64, 256, 0, stream>>>(out_w, OwT);

    // attention core -> o_nm (bf16 swizzled)
    k_attn_qkv<<<dim3(N_NODES / 2, BATCH), 192, 0, stream>>>(hq, hk, hv, onm);

    // out-proj + residual + LN1 (MFMA)
    k_outproj<<<ROWS / 64, 256, 0, stream>>>(onm, OwT, out_b, x, ln1_g, ln1_b, ln1, ln1bf);

    // FFN + residual + LN2 -> output
    k_ffn_mfma<<<ROWS / 64, 256, 0, stream>>>(ln1bf, ln1, W1T, ff_b1, W2R, ff_b2, ln2_g, ln2_b, (float*)d_out);
}

// Round 6
// 446.550 us; speedup vs baseline: 14.7071x; 1.0248x over previous
//
#include <hip/hip_runtime.h>
#include <cstddef>
#include <cstdint>

#define N_NODES 170
#define SEQ 12
#define BATCH 32
#define DM 120
#define BT (BATCH*SEQ)          // 384
#define ROWS (BT*N_NODES)       // 65280
#define FF 2048

typedef short short8 __attribute__((ext_vector_type(8)));
typedef float f32x4 __attribute__((ext_vector_type(4)));

// ---------------- workspace layout (floats) ----------------
static constexpr size_t OFF_A    = 0;          // 86,704
static constexpr size_t OFF_G    = 86704;
static constexpr size_t OFF_A2   = 173408;
static constexpr size_t OFF_L    = 260112;     // L_bf bf16 3*31808 ush = 47,712 fl
static constexpr size_t OFF_RS1  = 307824;
static constexpr size_t OFF_RS2  = 308336;
static constexpr size_t OFF_RS3  = 308848;
static constexpr size_t OFF_XT   = 309360;                   // 4,325,376 fl
static constexpr size_t OFF_XNM  = OFF_XT  + 4325376;        // 4,177,920 -> end 8,812,656
static constexpr size_t OFF_HK   = OFF_XNM + 4177920;        // 4,177,920
static constexpr size_t OFF_HV   = OFF_HK  + 4177920;        // 4,177,920 -> end 17,168,496
static constexpr size_t OFF_YNM  = OFF_HV  + 4177920;        // 3x8,355,840 -> end 42,236,016
static constexpr size_t OFF_BC   = OFF_YNM + 3*8355840;      // 73,728
static constexpr size_t OFF_W1T  = OFF_BC  + 73728;          // 131,072
static constexpr size_t OFF_W2R  = OFF_W1T + 131072;         // 131,072
static constexpr size_t OFF_OWT  = OFF_W2R + 131072;         // 8,192 -> end 42,580,080 (<47,350,016 proven)
// aliases inside ynm region (dead after combine):
static constexpr size_t OFF_HQ   = OFF_XT;                   // xT dead after lapply2
static constexpr size_t OFF_ONM  = OFF_YNM;                  // 4,177,920
static constexpr size_t OFF_LN1  = OFF_ONM + 4177920;        // 7,833,600
static constexpr size_t OFF_LN1B = OFF_LN1 + 7833600;        // 4,177,920 -> end 33,357,936 (inside ynm ✓)

static constexpr size_t YNM_BR_STRIDE = 16711680;  // ushorts per branch

__device__ __forceinline__ unsigned short f2bf(float f) {
    unsigned int u = __float_as_uint(f);
    unsigned int r = (u + 0x7fffu + ((u >> 16) & 1u)) >> 16;
    return (unsigned short)r;
}
__device__ __forceinline__ float bf2f(unsigned short h) {
    return __uint_as_float(((unsigned int)h) << 16);
}
__device__ __forceinline__ void gld16(const void* g, void* l) {
    __builtin_amdgcn_global_load_lds(
        (const __attribute__((address_space(1))) void*)g,
        (__attribute__((address_space(3))) void*)l, 16, 0, 0);
}
__device__ __forceinline__ uint4 pack8(const unsigned short v[8]) {
    uint4 q;
    q.x = (unsigned)v[0] | ((unsigned)v[1] << 16);
    q.y = (unsigned)v[2] | ((unsigned)v[3] << 16);
    q.z = (unsigned)v[4] | ((unsigned)v[5] << 16);
    q.w = (unsigned)v[6] | ((unsigned)v[7] << 16);
    return q;
}

// ================= graph-learn stage 1 =================
__global__ __launch_bounds__(256)
void k_gl1(const float* __restrict__ adj, const float* __restrict__ beta,
           const float* __restrict__ w1, const float* __restrict__ w2,
           const float* __restrict__ cw, const float* __restrict__ cb,
           float* __restrict__ a_out, float* __restrict__ rs_out) {
    int i  = blockIdx.x;
    int br = blockIdx.y;
    __shared__ float w1r[DM], w2r[DM];
    __shared__ float red[256];
    int tid = threadIdx.x;
    const float* w1b = w1 + (size_t)br * N_NODES * DM;
    const float* w2b = w2 + (size_t)br * N_NODES * DM;
    if (tid < DM) {
        w1r[tid] = w1b[(size_t)i * DM + tid];
        w2r[tid] = w2b[(size_t)i * DM + tid];
    }
    __syncthreads();
    float aval = 0.f;
    if (tid < N_NODES) {
        int j = tid;
        const float4* w1j = (const float4*)(w1b + (size_t)j * DM);
        const float4* w2j = (const float4*)(w2b + (size_t)j * DM);
        float s1 = 0.f, s2 = 0.f;
#pragma unroll 6
        for (int cc = 0; cc < DM / 4; ++cc) {
            float4 u = w2j[cc];
            float4 v = w1j[cc];
            s1 += w1r[cc*4+0]*u.x + w1r[cc*4+1]*u.y + w1r[cc*4+2]*u.z + w1r[cc*4+3]*u.w;
            s2 += w2r[cc*4+0]*v.x + w2r[cc*4+1]*v.y + w2r[cc*4+2]*v.z + w2r[cc*4+3]*v.w;
        }
        float nv = s1 - s2 + (j == i ? beta[br * N_NODES + i] : 0.f);
        nv = fmaxf(nv, 0.f);
        float adjv = adj[(size_t)i * N_NODES + j];
        float z = cw[br*2+0] * nv + cw[br*2+1] * adjv + cb[br];
        float gate = 1.f / (1.f + __expf(-z));
        aval = gate * nv + (1.f - gate) * adjv;
        a_out[((size_t)br * N_NODES + i) * N_NODES + j] = aval;
    }
    red[tid] = aval;
    __syncthreads();
    for (int s = 128; s > 0; s >>= 1) {
        if (tid < s) red[tid] += red[tid + s];
        __syncthreads();
    }
    if (tid == 0) rs_out[br * N_NODES + i] = red[0];
}

// ================= graph-learn normalize passes (modes 2,3) =================
__global__ __launch_bounds__(256)
void k_glnorm(const float* __restrict__ in, const float* __restrict__ rs,
              float* __restrict__ out, float* __restrict__ rs_out, int mode) {
    int i  = blockIdx.x;
    int br = blockIdx.y;
    __shared__ float red[256];
    int tid = threadIdx.x;
    float di = rsqrtf(rs[br * N_NODES + i]);
    float contrib = 0.f;
    if (tid < N_NODES) {
        float dj = rsqrtf(rs[br * N_NODES + tid]);
        float v = di * in[((size_t)br * N_NODES + i) * N_NODES + tid] * dj;
        float o;
        if (mode == 2) { o = fmaxf(v - 0.5f / 170.f, 0.f); contrib = o; }
        else           { o = v; contrib = v; }
        out[((size_t)br * N_NODES + i) * N_NODES + tid] = o;
    }
    red[tid] = contrib;
    __syncthreads();
    for (int s = 128; s > 0; s >>= 1) {
        if (tid < s) red[tid] += red[tid + s];
        __syncthreads();
    }
    if (tid == 0) rs_out[br * N_NODES + i] = red[0];
}

// ================= L prep: L_bf[br][176][180] bf16, zero-padded =================
__global__ __launch_bounds__(192)
void k_prep_L(const float* __restrict__ g_buf, const float* __restrict__ rs3,
              unsigned short* __restrict__ Lbf) {
    int i  = blockIdx.x;   // 0..175
    int br = blockIdx.y;
    int j  = threadIdx.x;
    if (j >= 180) return;
    float v = 0.f;
    if (i < N_NODES && j < N_NODES) {
        float di = rsqrtf(rs3[br * N_NODES + i]);
        float dj = rsqrtf(rs3[br * N_NODES + j]);
        float gg = g_buf[((size_t)br * N_NODES + i) * N_NODES + j];
        v = (i == j ? 1.f : 0.f) - di * gg * dj;
    }
    Lbf[(size_t)br * 31808 + i * 180 + j] = f2bf(v);
}

// ================= x prep: xTF (frag-linear channel-major) + x_nm (node-major swizzled) =========
__global__ __launch_bounds__(256)
void k_prep_x(const float* __restrict__ x, unsigned short* __restrict__ xTF,
              unsigned short* __restrict__ xnm) {
    __shared__ unsigned short LX[170 * 121 + 8];
    int bt = blockIdx.x, tid = threadIdx.x;
    const float* xb = x + (size_t)bt * N_NODES * DM;
    for (int u = tid; u < 170 * 30; u += 256) {
        int nn = u / 30, cq = u - nn * 30;
        float4 v = *(const float4*)&xb[nn * 120 + cq * 4];
        LX[nn * 121 + cq * 4 + 0] = f2bf(v.x);
        LX[nn * 121 + cq * 4 + 1] = f2bf(v.y);
        LX[nn * 121 + cq * 4 + 2] = f2bf(v.z);
        LX[nn * 121 + cq * 4 + 3] = f2bf(v.w);
    }
    __syncthreads();
    for (int u = tid; u < 128 * 22; u += 256) {
        int c = u / 22, mb = u - c * 22;
        unsigned short vals[8];
#pragma unroll
        for (int i2 = 0; i2 < 8; ++i2) {
            int m = mb * 8 + i2;
            vals[i2] = (c < 120 && m < 170) ? LX[m * 121 + c] : (unsigned short)0;
        }
        *(uint4*)&xTF[(size_t)bt * 22528 + ((size_t)mb * 128 + c) * 8] = pack8(vals);
    }
    for (int u = tid; u < 170 * 16; u += 256) {
        int nn = u >> 4, b = u & 15;
        unsigned int row = bt * 170 + nn;
        unsigned short vals[8];
#pragma unroll
        for (int i2 = 0; i2 < 8; ++i2) {
            int c = b * 8 + i2;
            vals[i2] = (c < 120) ? LX[nn * 121 + c] : (unsigned short)0;
        }
        int bs = (b & 8) | ((b & 7) ^ (row & 7));
        *(uint4*)&xnm[(size_t)row * 128 + bs * 8] = pack8(vals);
    }
}

// ================= merged weight prep: W1T, W2R, OwT, Bc (all frag layouts) =================
__global__ __launch_bounds__(256)
void k_prep_weights(const float* __restrict__ ff_w1, const float* __restrict__ ff_w2,
                    const float* __restrict__ out_w, const float* __restrict__ cheb_w,
                    unsigned short* __restrict__ W1T, unsigned short* __restrict__ W2R,
                    unsigned short* __restrict__ OwT, unsigned short* __restrict__ Bc) {
    int idx = blockIdx.x * 256 + threadIdx.x;
    if (idx < 262144) {                     // W1T[o][kpos] swizzled
        int o = idx >> 7, k = idx & 127;
        int b = k >> 3, ki = k & 7;
        int pos = (((b ^ (o & 7)) << 3) | ki);
        float v = (k < DM) ? ff_w1[(size_t)k * FF + o] : 0.f;
        W1T[(size_t)o * 128 + pos] = f2bf(v);
    } else if (idx < 524288) {              // W2R[c][o][jpos] swizzled
        int i = idx - 262144;
        int c = i >> 13;
        int o = (i >> 6) & 127;
        int j = i & 63;
        int b = j >> 3, ji = j & 7;
        int pos = (((b ^ (o & 7)) << 3) | ji);
        float v = (o < DM) ? ff_w2[(size_t)(c * 64 + j) * DM + o] : 0.f;
        W2R[((size_t)c << 13) + (o << 6) + pos] = f2bf(v);
    } else if (idx < 540672) {              // OwT frag-linear
        int i = idx - 524288;
        int o = i >> 7, c = i & 127;
        float v = (o < 120 && c < 120) ? out_w[(size_t)c * 120 + o] : 0.f;
        OwT[(((size_t)(c >> 3) * 128 + o) << 3) + (c & 7)] = f2bf(v);
    } else {                                // Bc frag-linear
        int i = idx - 540672;               // 3*128*384
        int br  = i / 49152;
        int rem = i - br * 49152;
        int o   = rem / 384;
        int c   = rem - o * 384;
        float v = 0.f;
        if (o < 120) {
            int part = c >> 7, cc = c & 127;
            if (cc < 120) {
                const float* Wb = cheb_w + (size_t)br * 3 * 14400;
                if (part == 0)      v = Wb[cc * 120 + o] - Wb[2 * 14400 + cc * 120 + o];
                else if (part == 1) v = Wb[14400 + cc * 120 + o];
                else                v = 2.f * Wb[2 * 14400 + cc * 120 + o];
            }
        }
        Bc[(size_t)br * 49152 + (((size_t)(c >> 3) * 128 + o) << 3) + (c & 7)] = f2bf(v);
    }
}

// ================= fused double-hop L-apply: y1 = L-hop(x) (LDS), y2 = L-hop(y1) =================
// Writes both halves of ynm (coloff 0 and 128). Y1 kept in LDS [c][m], stride MP.
#define MP 184
__global__ __launch_bounds__(256)
void k_lapply2(const unsigned short* __restrict__ xTg,
               const unsigned short* __restrict__ Lg_base,
               unsigned short* __restrict__ ynm_base) {
    __shared__ __attribute__((aligned(16))) unsigned short Llds[31744];   // 63488 B
    __shared__ __attribute__((aligned(16))) unsigned short Y1[128 * MP];  // 47104 B
    const int tid = threadIdx.x, w = tid >> 6, lane = tid & 63;
    const int g = lane >> 4, l15 = lane & 15;
    const int bt = blockIdx.x, br = blockIdx.y;
    const unsigned short* Asrc = xTg + (size_t)bt * 22528;
    const unsigned short* Lg   = Lg_base + (size_t)br * 31808;
    unsigned short* ynm = ynm_base + (size_t)br * YNM_BR_STRIDE;
    // stage L (63360 B used, staged in 1KB segments)
    const char* Lgb = (const char*)Lg;
    char* Lldsb = (char*)Llds;
#pragma unroll
    for (int it = 0; it < 16; ++it) {
        int q = it * 4 + w;
        if (q * 1024 < 63360)
            gld16(Lgb + q * 1024 + lane * 16, Lldsb + q * 1024);
    }
    // hop-1 A-frags from global (frag-linear)
    short8 af[2][6];
#pragma unroll
    for (int ct2 = 0; ct2 < 2; ++ct2) {
        int c = (w * 2 + ct2) * 16 + l15;
#pragma unroll
        for (int kb = 0; kb < 6; ++kb) {
            if (kb < 5) af[ct2][kb] = *(const short8*)&Asrc[(((size_t)(kb * 4 + g)) * 128 + c) * 8];
            else {
                short8 z = {};
                af[ct2][kb] = (g < 2) ? *(const short8*)&Asrc[(((size_t)(20 + g)) * 128 + c) * 8] : z;
            }
        }
    }
    __syncthreads();
    f32x4 acc[2][11];

    for (int hop = 0; hop < 2; ++hop) {
#pragma unroll
        for (int a = 0; a < 2; ++a)
#pragma unroll
            for (int b = 0; b < 11; ++b) acc[a][b] = (f32x4){0.f, 0.f, 0.f, 0.f};
#pragma unroll
        for (int kb = 0; kb < 6; ++kb) {
#pragma unroll
            for (int nt = 0; nt < 11; ++nt) {
                short8 bf;
                int rb = (nt * 16 + l15) * 180;
                if (kb < 5) bf = *(const short8*)&Llds[rb + kb * 32 + g * 8];
                else {
                    short8 z = {};
                    bf = (g < 2) ? *(const short8*)&Llds[rb + 160 + g * 8] : z;
                }
                acc[0][nt] = __builtin_amdgcn_mfma_f32_16x16x32_bf16(af[0][kb], bf, acc[0][nt], 0, 0, 0);
                acc[1][nt] = __builtin_amdgcn_mfma_f32_16x16x32_bf16(af[1][kb], bf, acc[1][nt], 0, 0, 0);
            }
        }
        const int coloff = hop * 128;
        // stores: ynm half; hop 0 additionally fills Y1 (LDS)
#pragma unroll
        for (int nt = 0; nt < 11; ++nt) {
            int nn = nt * 16 + l15;
#pragma unroll
            for (int ct2 = 0; ct2 < 2; ++ct2) {
                int base_c = (w * 2 + ct2) * 16 + g * 4;
                if (hop == 0) {
#pragma unroll
                    for (int r = 0; r < 4; ++r)
                        Y1[(base_c + r) * MP + nn] = f2bf(acc[ct2][nt][r]);
                }
                if (nn < 170) {
                    unsigned int row = bt * 170 + nn;
                    unsigned short u[4];
#pragma unroll
                    for (int r = 0; r < 4; ++r)
                        u[r] = (base_c + r < 120) ? f2bf(acc[ct2][nt][r]) : (unsigned short)0;
                    int bc  = coloff + base_c;
                    int blk = bc >> 3;
                    int bsw = (blk & 24) | ((blk & 7) ^ (row & 7));
                    uint2 pk;
                    pk.x = (unsigned)u[0] | ((unsigned)u[1] << 16);
                    pk.y = (unsigned)u[2] | ((unsigned)u[3] << 16);
                    *(uint2*)&ynm[(size_t)row * 256 + bsw * 8 + (bc & 7)] = pk;
                }
            }
        }
        if (hop == 0) {
            __syncthreads();
            // hop-2 A-frags from Y1 [c][m]
#pragma unroll
            for (int ct2 = 0; ct2 < 2; ++ct2) {
                int c = (w * 2 + ct2) * 16 + l15;
#pragma unroll
                for (int kb = 0; kb < 6; ++kb) {
                    if (kb < 5) af[ct2][kb] = *(const short8*)&Y1[c * MP + kb * 32 + g * 8];
                    else {
                        short8 z = {};
                        af[ct2][kb] = (g < 2) ? *(const short8*)&Y1[c * MP + 160 + g * 8] : z;
                    }
                }
            }
        }
    }
}

// ================= MFMA Cheb combine (frag-linear B) =================
__global__ __launch_bounds__(256)
void k_combine_mfma(const unsigned short* __restrict__ xnm,
                    const unsigned short* __restrict__ ynm_base,
                    const unsigned short* __restrict__ Bc_base,
                    const float* __restrict__ bias_base,
                    unsigned short* __restrict__ h0,
                    unsigned short* __restrict__ h1,
                    unsigned short* __restrict__ h2) {
    __shared__ __attribute__((aligned(16))) unsigned short AsX[64 * 128];
    __shared__ __attribute__((aligned(16))) unsigned short AsY[64 * 256];
    const int tid = threadIdx.x, w = tid >> 6, lane = tid & 63;
    const int g = lane >> 4, l15 = lane & 15;
    const int r0 = blockIdx.x * 64;
    const int br = blockIdx.y;
    const unsigned short* ynm = ynm_base + (size_t)br * YNM_BR_STRIDE;
    const unsigned short* Bc  = Bc_base + (size_t)br * 49152;
    const float* bias = bias_base + br * DM;
    unsigned short* Hout = (br == 0) ? h0 : (br == 1) ? h1 : h2;
#pragma unroll
    for (int it = 0; it < 4; ++it) {
        int q = w * 4 + it;
        gld16(xnm + (size_t)r0 * 128 + q * 512 + lane * 8, &AsX[q * 512]);
    }
#pragma unroll
    for (int it = 0; it < 8; ++it) {
        int q = w * 8 + it;
        gld16(ynm + (size_t)r0 * 256 + q * 512 + lane * 8, &AsY[q * 512]);
    }
    __syncthreads();
    const int lr = w * 16 + l15;
    short8 af[12];
#pragma unroll
    for (int kb = 0; kb < 4; ++kb) {
        int b = kb * 4 + g;
        int bs = (b & 8) | ((b & 7) ^ (lr & 7));
        af[kb] = *(const short8*)&AsX[lr * 128 + bs * 8];
    }
#pragma unroll
    for (int kb = 4; kb < 12; ++kb) {
        int b = (kb - 4) * 4 + g;
        int bs = (b & 24) | ((b & 7) ^ (lr & 7));
        af[kb] = *(const short8*)&AsY[lr * 256 + bs * 8];
    }
    f32x4 acc[8];
#pragma unroll
    for (int c = 0; c < 8; ++c) acc[c] = (f32x4){0.f, 0.f, 0.f, 0.f};
    short8 bfA[8], bfB[8];
#pragma unroll
    for (int c = 0; c < 8; ++c)
        bfA[c] = *(const short8*)&Bc[(((size_t)g) * 128 + c * 16 + l15) * 8];
#pragma unroll
    for (int kb = 0; kb < 12; ++kb) {
        if (kb + 1 < 12) {
#pragma unroll
            for (int c = 0; c < 8; ++c) {
                short8 v = *(const short8*)&Bc[(((size_t)((kb + 1) * 4 + g)) * 128 + c * 16 + l15) * 8];
                if (kb & 1) bfA[c] = v; else bfB[c] = v;
            }
        }
#pragma unroll
        for (int c = 0; c < 8; ++c)
            acc[c] = __builtin_amdgcn_mfma_f32_16x16x32_bf16(af[kb], (kb & 1) ? bfB[c] : bfA[c], acc[c], 0, 0, 0);
    }
#pragma unroll
    for (int c = 0; c < 8; ++c) {
        int o = c * 16 + l15;
        float bv = (o < 120) ? bias[o] : 0.f;
#pragma unroll
        for (int r = 0; r < 4; ++r) {
            int row = r0 + w * 16 + g * 4 + r;
            float v = (o < 120) ? fmaxf(acc[c][r] + bv, 0.f) : 0.f;
            Hout[(size_t)row * 128 + o] = f2bf(v);
        }
    }
}

// ================= attention core: softmax(QK^T/s)V per (b, 2 nodes) =================
#define QP 136
__global__ __launch_bounds__(192)
void k_attn_qkv(const unsigned short* __restrict__ hq, const unsigned short* __restrict__ hk,
                const unsigned short* __restrict__ hv, unsigned short* __restrict__ onm) {
    __shared__ unsigned short qs[2][SEQ][QP], ks[2][SEQ][QP], vs[2][SEQ][QP], os[2][SEQ][QP];
    const int tid = threadIdx.x;
    const int np = blockIdx.x, b = blockIdx.y;
    for (int u = tid; u < 2 * SEQ * 16; u += 192) {
        int node = u / (SEQ * 16);
        int rem = u - node * SEQ * 16;
        int t = rem >> 4, seg = rem & 15;
        int n = np * 2 + node;
        size_t row = ((size_t)(b * SEQ + t) * N_NODES + n);
        *(uint4*)&qs[node][t][seg * 8] = *(const uint4*)&hq[row * 128 + seg * 8];
        *(uint4*)&ks[node][t][seg * 8] = *(const uint4*)&hk[row * 128 + seg * 8];
        *(uint4*)&vs[node][t][seg * 8] = *(const uint4*)&hv[row * 128 + seg * 8];
    }
    __syncthreads();
    {
        const int node = tid / 96, sub = tid % 96;
        const int h = sub & 7, tq = sub >> 3;
        float qr[15];
#pragma unroll
        for (int d = 0; d < 15; ++d) qr[d] = bf2f(qs[node][tq][h * 15 + d]);
        float sc[SEQ];
        float mx = -1e30f;
#pragma unroll
        for (int tk = 0; tk < SEQ; ++tk) {
            float s = 0.f;
#pragma unroll
            for (int d = 0; d < 15; ++d) s += qr[d] * bf2f(ks[node][tk][h * 15 + d]);
            s *= 0.25819888974716113f;
            sc[tk] = s;
            mx = fmaxf(mx, s);
        }
        float sum = 0.f;
#pragma unroll
        for (int tk = 0; tk < SEQ; ++tk) { sc[tk] = __expf(sc[tk] - mx); sum += sc[tk]; }
        float inv = 1.f / sum;
#pragma unroll
        for (int d = 0; d < 15; ++d) {
            float o = 0.f;
#pragma unroll
            for (int tk = 0; tk < SEQ; ++tk) o += sc[tk] * bf2f(vs[node][tk][h * 15 + d]);
            os[node][tq][h * 15 + d] = f2bf(o * inv);
        }
    }
    if (tid < 2 * SEQ) {
        int node = tid / SEQ, t = tid % SEQ;
#pragma unroll
        for (int j = 0; j < 8; ++j) os[node][t][120 + j] = 0;
    }
    __syncthreads();
    for (int u = tid; u < 2 * SEQ * 16; u += 192) {
        int node = u / (SEQ * 16);
        int rem = u - node * SEQ * 16;
        int t = rem >> 4, seg = rem & 15;
        int n = np * 2 + node;
        unsigned int row = (b * SEQ + t) * N_NODES + n;
        int bs = (seg & 8) | ((seg & 7) ^ (row & 7));
        *(uint4*)&onm[(size_t)row * 128 + bs * 8] = *(const uint4*)&os[node][t][seg * 8];
    }
}

// ================= MFMA out-proj + residual + LN1 (frag-linear B) =================
__global__ __launch_bounds__(256)
void k_outproj(const unsigned short* __restrict__ onm, const unsigned short* __restrict__ OwT,
               const float* __restrict__ outb, const float* __restrict__ x,
               const float* __restrict__ g1, const float* __restrict__ be1,
               float* __restrict__ ln1, unsigned short* __restrict__ ln1bf) {
    __shared__ __attribute__((aligned(16))) unsigned short As[64 * 128];
    const int tid = threadIdx.x, w = tid >> 6, lane = tid & 63;
    const int g = lane >> 4, l15 = lane & 15;
    const int r0 = blockIdx.x * 64;
#pragma unroll
    for (int it = 0; it < 4; ++it) {
        int q = w * 4 + it;
        gld16(onm + (size_t)r0 * 128 + q * 512 + lane * 8, &As[q * 512]);
    }
    __syncthreads();
    const int lr = w * 16 + l15;
    short8 af[4];
#pragma unroll
    for (int kb = 0; kb < 4; ++kb) {
        int b = kb * 4 + g;
        int bs = (b & 8) | ((b & 7) ^ (lr & 7));
        af[kb] = *(const short8*)&As[lr * 128 + bs * 8];
    }
    f32x4 acc[8];
#pragma unroll
    for (int c = 0; c < 8; ++c) acc[c] = (f32x4){0.f, 0.f, 0.f, 0.f};
#pragma unroll
    for (int kb = 0; kb < 4; ++kb) {
#pragma unroll
        for (int c = 0; c < 8; ++c) {
            short8 bf = *(const short8*)&OwT[(((size_t)(kb * 4 + g)) * 128 + c * 16 + l15) * 8];
            acc[c] = __builtin_amdgcn_mfma_f32_16x16x32_bf16(af[kb], bf, acc[c], 0, 0, 0);
        }
    }
#pragma unroll
    for (int r = 0; r < 4; ++r) {
        int row = w * 16 + g * 4 + r;
        size_t grow = (size_t)(r0 + row);
        float vals[8];
        float s = 0.f, q = 0.f;
#pragma unroll
        for (int c = 0; c < 8; ++c) {
            int col = c * 16 + l15;
            float v = 0.f;
            if (col < DM) v = acc[c][r] + outb[col] + x[grow * DM + col];
            vals[c] = v;
            s += v; q += v * v;
        }
#pragma unroll
        for (int m = 1; m < 16; m <<= 1) {
            s += __shfl_xor(s, m);
            q += __shfl_xor(q, m);
        }
        float mean = s * (1.f / DM);
        float var  = q * (1.f / DM) - mean * mean;
        float rstd = rsqrtf(var + 1e-5f);
#pragma unroll
        for (int c = 0; c < 8; ++c) {
            int col = c * 16 + l15;
            float o = (vals[c] - mean) * rstd * ((col < DM) ? g1[col] : 0.f) + ((col < DM) ? be1[col] : 0.f);
            if (col < DM) ln1[grow * DM + col] = o;
            ln1bf[grow * 128 + col] = (col < DM) ? f2bf(o) : (unsigned short)0;
        }
    }
}

// ================= MFMA FFN: O = LN2( X + relu(X@W1+b1)@W2 + b2 ) =================
// Phase A uses SWAPPED operands: mfma(w1frag, xfrag) -> per-thread regs are 4 consecutive
// HIDDEN cols for one X-row -> uint2 HS stores (was 16 scalar b16).
#define LDS_XW1A 0
#define LDS_W1B  8192
#define LDS_W2A  16384
#define LDS_W2B  24576
#define LDS_HS   32768
__global__ __launch_bounds__(256, 2)
void k_ffn_mfma(const unsigned short* __restrict__ Xbf,
                const float* __restrict__ ln1,
                const unsigned short* __restrict__ W1T,
                const float* __restrict__ b1,
                const unsigned short* __restrict__ W2R,
                const float* __restrict__ b2,
                const float* __restrict__ g2, const float* __restrict__ be2,
                float* __restrict__ Out) {
    __shared__ unsigned short lds[37376];
    const int tid  = threadIdx.x;
    const int w    = tid >> 6;
    const int lane = tid & 63;
    const int g    = lane >> 4;
    const int l15  = lane & 15;
    const int r0   = blockIdx.x * 64;
    {
        const unsigned short* xsrc = Xbf + (size_t)r0 * 128;
#pragma unroll
        for (int it = 0; it < 4; ++it) {
            int seg = w * 4 + it;
            gld16(xsrc + seg * 512 + lane * 8, &lds[LDS_XW1A + seg * 512]);
        }
#pragma unroll
        for (int it = 0; it < 4; ++it) {
            int seg = w * 4 + it;
            gld16(W1T + seg * 512 + lane * 8, &lds[LDS_W1B + seg * 512]);
        }
#pragma unroll
        for (int it = 0; it < 4; ++it) {
            int seg = w * 4 + it;
            gld16(W2R + seg * 512 + lane * 8, &lds[LDS_W2A + seg * 512]);
        }
    }
    __syncthreads();
    short8 xfrag[4][4];
#pragma unroll
    for (int rt = 0; rt < 4; ++rt)
#pragma unroll
        for (int kk = 0; kk < 4; ++kk)
            xfrag[rt][kk] = *(const short8*)&lds[LDS_XW1A + (rt * 16 + l15) * 128 + kk * 32 + g * 8];

    f32x4 accO[8] = {};
    const int mycolA = w * 16 + l15;   // W1T row (hidden col group base)
    const int myrowB = w * 16 + l15;

    for (int t = 0; t < 32; ++t) {
        __syncthreads();
        const int p = t & 1;
        if (t + 1 < 32) {
            const unsigned short* w1src = W1T + (size_t)(t + 1) * 8192;
            const unsigned short* w2src = W2R + (size_t)(t + 1) * 8192;
            unsigned short* w1dst = &lds[(p ? LDS_W1B : LDS_XW1A)];
            unsigned short* w2dst = &lds[(p ? LDS_W2A : LDS_W2B)];
#pragma unroll
            for (int it = 0; it < 4; ++it) {
                int seg = w * 4 + it;
                gld16(w1src + seg * 512 + lane * 8, w1dst + seg * 512);
                gld16(w2src + seg * 512 + lane * 8, w2dst + seg * 512);
            }
        }
        {
            const unsigned short* w1p = &lds[p ? LDS_XW1A : LDS_W1B];
            f32x4 accA[4] = {};
#pragma unroll
            for (int kk = 0; kk < 4; ++kk) {
                int b = kk * 4 + g;
                short8 bfrag = *(const short8*)&w1p[mycolA * 128 + ((b ^ (mycolA & 7)) << 3)];
#pragma unroll
                for (int rt = 0; rt < 4; ++rt)
                    accA[rt] = __builtin_amdgcn_mfma_f32_16x16x32_bf16(bfrag, xfrag[rt][kk], accA[rt], 0, 0, 0);
            }
            // accA[rt][r] = H[x_row = rt*16 + l15][hidden col = w*16 + g*4 + r]
            float4 b4 = *(const float4*)&b1[t * 64 + w * 16 + g * 4];
            float bb[4] = {b4.x, b4.y, b4.z, b4.w};
#pragma unroll
            for (int rt = 0; rt < 4; ++rt) {
                unsigned short u[4];
#pragma unroll
                for (int r = 0; r < 4; ++r)
                    u[r] = f2bf(fmaxf(accA[rt][r] + bb[r], 0.f));
                uint2 pk;
                pk.x = (unsigned)u[0] | ((unsigned)u[1] << 16);
                pk.y = (unsigned)u[2] | ((unsigned)u[3] << 16);
                *(uint2*)&lds[LDS_HS + (rt * 16 + l15) * 72 + w * 16 + g * 4] = pk;
            }
        }
        asm volatile("s_waitcnt lgkmcnt(0)" ::: "memory");
        __builtin_amdgcn_sched_barrier(0);
        __builtin_amdgcn_s_barrier();
        {
            const unsigned short* w2p = &lds[p ? LDS_W2B : LDS_W2A];
#pragma unroll
            for (int kk = 0; kk < 2; ++kk) {
                short8 hfrag = *(const short8*)&lds[LDS_HS + myrowB * 72 + kk * 32 + g * 8];
                int b = kk * 4 + g;
#pragma unroll
                for (int c = 0; c < 8; ++c) {
                    int o = c * 16 + l15;
                    short8 w2frag = *(const short8*)&w2p[(o << 6) + ((b ^ (o & 7)) << 3)];
                    accO[c] = __builtin_amdgcn_mfma_f32_16x16x32_bf16(hfrag, w2frag, accO[c], 0, 0, 0);
                }
            }
        }
    }
#pragma unroll
    for (int r = 0; r < 4; ++r) {
        int row = w * 16 + g * 4 + r;
        size_t grow = (size_t)(r0 + row);
        float vals[8];
        float s = 0.f, q = 0.f;
#pragma unroll
        for (int c = 0; c < 8; ++c) {
            int col = c * 16 + l15;
            float v = 0.f;
            if (col < DM) v = accO[c][r] + b2[col] + ln1[grow * DM + col];
            vals[c] = v;
            s += v; q += v * v;
        }
#pragma unroll
        for (int m = 1; m < 16; m <<= 1) {
            s += __shfl_xor(s, m);
            q += __shfl_xor(q, m);
        }
        float mean = s * (1.f / DM);
        float var  = q * (1.f / DM) - mean * mean;
        float rstd = rsqrtf(var + 1e-5f);
#pragma unroll
        for (int c = 0; c < 8; ++c) {
            int col = c * 16 + l15;
            if (col < DM)
                Out[grow * DM + col] = (vals[c] - mean) * rstd * g2[col] + be2[col];
        }
    }
}

// ================================ launch ================================
extern "C" void kernel_launch(void* const* d_in, const int* in_sizes, int n_in,
                              void* d_out, int out_size, void* d_ws, size_t ws_size,
                              hipStream_t stream) {
    const float* x      = (const float*)d_in[0];
    const float* adj    = (const float*)d_in[1];
    const float* gl_beta= (const float*)d_in[2];
    const float* gl_w1  = (const float*)d_in[3];
    const float* gl_w2  = (const float*)d_in[4];
    const float* gl_cw  = (const float*)d_in[5];
    const float* gl_cb  = (const float*)d_in[6];
    const float* cheb_w = (const float*)d_in[7];
    const float* cheb_b = (const float*)d_in[8];
    const float* out_w  = (const float*)d_in[9];
    const float* out_b  = (const float*)d_in[10];
    const float* ff_w1  = (const float*)d_in[11];
    const float* ff_b1  = (const float*)d_in[12];
    const float* ff_w2  = (const float*)d_in[13];
    const float* ff_b2  = (const float*)d_in[14];
    const float* ln1_g  = (const float*)d_in[15];
    const float* ln1_b  = (const float*)d_in[16];
    const float* ln2_g  = (const float*)d_in[17];
    const float* ln2_b  = (const float*)d_in[18];

    float* ws    = (float*)d_ws;
    float* a_buf = ws + OFF_A;
    float* g_buf = ws + OFF_G;
    float* a2buf = ws + OFF_A2;
    float* rs1   = ws + OFF_RS1;
    float* rs2   = ws + OFF_RS2;
    float* rs3   = ws + OFF_RS3;
    unsigned short* L_bf = (unsigned short*)(ws + OFF_L);
    unsigned short* xT   = (unsigned short*)(ws + OFF_XT);
    unsigned short* xnm  = (unsigned short*)(ws + OFF_XNM);
    unsigned short* ynm  = (unsigned short*)(ws + OFF_YNM);
    unsigned short* Bc   = (unsigned short*)(ws + OFF_BC);
    unsigned short* hq   = (unsigned short*)(ws + OFF_HQ);
    unsigned short* hk   = (unsigned short*)(ws + OFF_HK);
    unsigned short* hv   = (unsigned short*)(ws + OFF_HV);
    unsigned short* W1T  = (unsigned short*)(ws + OFF_W1T);
    unsigned short* W2R  = (unsigned short*)(ws + OFF_W2R);
    unsigned short* OwT  = (unsigned short*)(ws + OFF_OWT);
    unsigned short* onm  = (unsigned short*)(ws + OFF_ONM);
    float*          ln1  = ws + OFF_LN1;
    unsigned short* ln1bf= (unsigned short*)(ws + OFF_LN1B);

    // weight preps (dedicated regions; independent of everything else)
    k_prep_weights<<<2688, 256, 0, stream>>>(ff_w1, ff_w2, out_w, cheb_w, W1T, W2R, OwT, Bc);

    // graph learning
    k_gl1   <<<dim3(N_NODES, 3), 256, 0, stream>>>(adj, gl_beta, gl_w1, gl_w2, gl_cw, gl_cb, a_buf, rs1);
    k_glnorm<<<dim3(N_NODES, 3), 256, 0, stream>>>(a_buf, rs1, a2buf, rs2, 2);
    k_glnorm<<<dim3(N_NODES, 3), 256, 0, stream>>>(a2buf, rs2, g_buf, rs3, 3);
    k_prep_L<<<dim3(176, 3), 192, 0, stream>>>(g_buf, rs3, L_bf);

    // x prep
    k_prep_x<<<BT, 256, 0, stream>>>(x, xT, xnm);

    // fused double-hop Cheb L-apply (all branches)
    k_lapply2<<<dim3(BT, 3), 256, 0, stream>>>(xT, L_bf, ynm);

    // Cheb combine (all branches)
    k_combine_mfma<<<dim3(ROWS / 64, 3), 256, 0, stream>>>(xnm, ynm, Bc, cheb_b, hq, hk, hv);

    // attention core -> o_nm (bf16 swizzled)
    k_attn_qkv<<<dim3(N_NODES / 2, BATCH), 192, 0, stream>>>(hq, hk, hv, onm);

    // out-proj + residual + LN1 (MFMA)
    k_outproj<<<ROWS / 64, 256, 0, stream>>>(onm, OwT, out_b, x, ln1_g, ln1_b, ln1, ln1bf);

    // FFN + residual + LN2 -> output
    k_ffn_mfma<<<ROWS / 64, 256, 0, stream>>>(ln1bf, ln1, W1T, ff_b1, W2R, ff_b2, ln2_g, ln2_b, (float*)d_out);
}